// Round 11
// baseline (169.489 us; speedup 1.0000x reference)
//
#include <hip/hip_runtime.h>
#include <hip/hip_cooperative_groups.h>
#include <math.h>

namespace cg = cooperative_groups;

#define EMBED   1024
#define THREEC  3072
#define NH      16
#define HD      64
#define NFEAT   64      // R * M = 2 * 32
#define RN      2
#define MM_     32
#define B_      2
#define T_      4096
#define L_      64      // chunk length
#define NC_     64      // T_ / L_
#define BH_     32      // B_ * NH

typedef __attribute__((ext_vector_type(8))) short bf16x8;
typedef __attribute__((ext_vector_type(4))) short bf16x4;
typedef __attribute__((ext_vector_type(4))) float f32x4;

__device__ __forceinline__ float bf2f(short s) {
    unsigned u = ((unsigned)(unsigned short)s) << 16;
    return __builtin_bit_cast(float, u);
}
__device__ __forceinline__ short f2bf(float f) {
    unsigned u = __builtin_bit_cast(unsigned, f);
    u += 0x7fff + ((u >> 16) & 1);
    return (short)(u >> 16);
}
__device__ __forceinline__ void gload16(const short* g, short* l) {
    __builtin_amdgcn_global_load_lds(
        (const __attribute__((address_space(1))) void*)g,
        (__attribute__((address_space(3))) void*)l, 16, 0, 0);
}

// ---------------------------------------------------------------------------
// Fused prep: f32->bf16 casts for x, w_qkv, w_out + omega hi/lo transpose.
// ---------------------------------------------------------------------------
#define NV_X   1048576            // 8388608 / 8
#define NV_WQ  393216             // 3145728 / 8
#define NV_WO  131072             // 1048576 / 8
#define NV_ALL (NV_X + NV_WQ + NV_WO)
__global__ __launch_bounds__(256) void prep_kernel(
    const float* __restrict__ x, const float* __restrict__ wq,
    const float* __restrict__ wo, const float* __restrict__ omega,
    short* __restrict__ xb, short* __restrict__ wqb, short* __restrict__ wob,
    short* __restrict__ omgH, short* __restrict__ omgL)
{
    int i = blockIdx.x * 256 + threadIdx.x;
    if (i < NV_ALL) {
        const float* src; short* dst; int k;
        if (i < NV_X)            { src = x;  dst = xb;  k = i; }
        else if (i < NV_X+NV_WQ) { src = wq; dst = wqb; k = i - NV_X; }
        else                     { src = wo; dst = wob; k = i - NV_X - NV_WQ; }
        const float4* p = (const float4*)src + (size_t)k * 2;
        float4 a = p[0], b = p[1];
        bf16x8 o = { f2bf(a.x), f2bf(a.y), f2bf(a.z), f2bf(a.w),
                     f2bf(b.x), f2bf(b.y), f2bf(b.z), f2bf(b.w) };
        *((bf16x8*)dst + k) = o;
    } else {
        int j = i - NV_ALL;               // 0..65535 over H*F*D
        if (j < NH * NFEAT * HD) {
            int d = j & 63;
            int f = (j >> 6) & 63;
            int h = j >> 12;
            int r = f >> 5, m = f & 31;
            float w = omega[(((size_t)(r * NH + h) * HD + d) * MM_) + m];
            short a = f2bf(w);
            omgH[j] = a;
            omgL[j] = f2bf(w - bf2f(a));
        }
    }
}

// ---------------------------------------------------------------------------
// bf16 MFMA GEMM (m97 structure), 1D grid + XCD-aware M-stripe swizzle.
// ---------------------------------------------------------------------------
template<int OUTBF>
__global__ __launch_bounds__(256) void gemm_bf16(
    const short* __restrict__ A,      // [M][K] bf16
    const short* __restrict__ W,      // [N][K] bf16
    const float* __restrict__ bias,   // [N]
    float* __restrict__ Cf, short* __restrict__ Cb,
    int M, int N, int K)
{
    __shared__ short lA[2][128 * 32];
    __shared__ short lB[2][128 * 32];
    const int tid  = threadIdx.x;
    const int nbn  = N >> 7;
    const int cpx  = gridDim.x >> 3;
    const int swz  = (blockIdx.x & 7) * cpx + (blockIdx.x >> 3);
    const int bm   = (swz / nbn) << 7;
    const int bn   = (swz % nbn) << 7;
    const int lane = tid & 63;
    const int wave = tid >> 6;
    const int row0 = (wave >> 1) * 64;
    const int col0 = (wave & 1) * 64;
    const int lr   = lane & 15;
    const int kg8  = (lane >> 4) * 8;

    f32x4 acc[4][4] = {};

#define STAGE(buf, k0)                                                        \
    {                                                                         \
        _Pragma("unroll")                                                     \
        for (int i = 0; i < 2; ++i) {                                         \
            int idx = i * 256 + tid;                                          \
            int row = idx >> 2, kq = (idx & 3) * 8;                           \
            gload16(&A[(size_t)(bm + row) * K + (k0) + kq], &lA[buf][idx * 8]); \
            gload16(&W[(size_t)(bn + row) * K + (k0) + kq], &lB[buf][idx * 8]); \
        }                                                                     \
    }

    const int KT = K >> 5;
    STAGE(0, 0);
    __syncthreads();
    int cur = 0;
    for (int kt = 0; kt < KT; ++kt) {
        if (kt + 1 < KT) STAGE(cur ^ 1, (kt + 1) * 32);
        const short* As = lA[cur];
        const short* Bs = lB[cur];
        bf16x8 af[4], bfr[4];
        #pragma unroll
        for (int m = 0; m < 4; ++m)
            af[m] = *(const bf16x8*)&As[(row0 + m * 16 + lr) * 32 + kg8];
        #pragma unroll
        for (int n = 0; n < 4; ++n)
            bfr[n] = *(const bf16x8*)&Bs[(col0 + n * 16 + lr) * 32 + kg8];
        #pragma unroll
        for (int m = 0; m < 4; ++m)
            #pragma unroll
            for (int n = 0; n < 4; ++n)
                acc[m][n] = __builtin_amdgcn_mfma_f32_16x16x32_bf16(
                    af[m], bfr[n], acc[m][n], 0, 0, 0);
        __syncthreads();
        cur ^= 1;
    }
#undef STAGE

    #pragma unroll
    for (int n = 0; n < 4; ++n) {
        const int col = bn + col0 + n * 16 + (lane & 15);
        const float bvv = bias[col];
        #pragma unroll
        for (int m = 0; m < 4; ++m) {
            const int rbase = bm + row0 + m * 16 + (lane >> 4) * 4;
            #pragma unroll
            for (int j = 0; j < 4; ++j) {
                const float v = acc[m][n][j] + bvv;
                if (OUTBF) Cb[(size_t)(rbase + j) * N + col] = f2bf(v);
                else       Cf[(size_t)(rbase + j) * N + col] = v;
            }
        }
    }
}

// ===========================================================================
// MEGA cooperative kernel: feat + chunk sums + intra (phase A, 2 chunks/blk)
//  -> grid sync -> prefix (blocks < 128) -> grid sync -> inter (phase C).
// Q fragments (aqR) + rowsums (rsR) retained in registers across syncs, so
// qf never touches global. qkp computed via MFMA with cKp as B-column 0.
// ===========================================================================
__global__ __launch_bounds__(256, 4) void mega_attn(
    const short* __restrict__ qkvb,
    const short* __restrict__ omgH,
    const short* __restrict__ omgL,
    const float* __restrict__ qn,
    const float* __restrict__ qw,
    short* __restrict__ ctxb,
    short* __restrict__ cKVb,
    float* __restrict__ cK,
    short* __restrict__ attnb)
{
    __shared__ short zq[64][72];
    __shared__ short zk[64][72];
    __shared__ short omh[64][72];
    __shared__ short oml[64][72];
    __shared__ float invn[2][64];

    const int tid  = threadIdx.x;
    const int g    = blockIdx.x;
    const int wave = tid >> 6;
    const int lane = tid & 63;
    const int lr   = lane & 15;
    const int G    = lane >> 4;
    const int kg8  = G * 8;
    const int r0   = wave * 16;

    bf16x8 aqR0[2], aqR1[2];
    float  rsR0[4], rsR1[4];

    // ------------------------- phase A: 2 chunks ------------------------
    #pragma unroll
    for (int cc = 0; cc < 2; ++cc) {
        const int chunk = 2 * g + cc;
        const int bh = chunk >> 6, c = chunk & 63;
        const int b = bh >> 4, h = bh & 15;
        const int t0 = c * 64;
        __syncthreads();   // protect LDS reuse across iterations
        {
            const int row = tid >> 2;
            const int c0  = (tid & 3) * 16;
            const size_t zbase = ((size_t)(b * T_ + t0 + row)) * THREEC + h * HD + c0;
            const size_t obase = ((size_t)h * NFEAT + row) * HD + c0;
            *(bf16x8*)&zq[row][c0]      = *(const bf16x8*)&qkvb[zbase];
            *(bf16x8*)&zq[row][c0 + 8]  = *(const bf16x8*)&qkvb[zbase + 8];
            *(bf16x8*)&zk[row][c0]      = *(const bf16x8*)&qkvb[zbase + EMBED];
            *(bf16x8*)&zk[row][c0 + 8]  = *(const bf16x8*)&qkvb[zbase + EMBED + 8];
            *(bf16x8*)&omh[row][c0]     = *(const bf16x8*)&omgH[obase];
            *(bf16x8*)&omh[row][c0 + 8] = *(const bf16x8*)&omgH[obase + 8];
            *(bf16x8*)&oml[row][c0]     = *(const bf16x8*)&omgL[obase];
            *(bf16x8*)&oml[row][c0 + 8] = *(const bf16x8*)&omgL[obase + 8];
        }
        __syncthreads();
        {
            const int t = tid >> 2;
            const int q = tid & 3;
            #pragma unroll
            for (int p = 0; p < 2; ++p) {
                const short* Z = p ? &zk[t][q * 16] : &zq[t][q * 16];
                float ss = 0.0f;
                #pragma unroll
                for (int j = 0; j < 16; ++j) { float v = bf2f(Z[j]); ss += v * v; }
                ss += __shfl_xor(ss, 1, 64);
                ss += __shfl_xor(ss, 2, 64);
                if (q == 0) invn[p][t] = 1.0f / fmaxf(sqrtf(ss), 1e-12f);
            }
        }
        __syncthreads();

        const int p    = wave >> 1;
        const int half = wave & 1;
        const short (*Z)[72] = p ? zk : zq;

        const float s0 = qn[0], s1 = qn[1];
        const float sq2s0 = sqrtf(2.0f * fmaxf(s0, 0.0f));
        const float sq2s1 = sqrtf(2.0f * fmaxf(s1, 0.0f));
        const float sc0 = sqrtf(fmaxf(qw[0], 0.0f)) * (1.0f / 32.0f);
        const float sc1 = sqrtf(fmaxf(qw[1], 0.0f)) * (1.0f / 32.0f);

        f32x4 acc[2][4] = {};
        #pragma unroll
        for (int kk = 0; kk < 2; ++kk) {
            bf16x8 a[2], bh8[4], bl8[4];
            #pragma unroll
            for (int m = 0; m < 2; ++m)
                a[m] = *(const bf16x8*)&Z[half * 32 + m * 16 + lr][kk * 32 + kg8];
            #pragma unroll
            for (int n = 0; n < 4; ++n) {
                bh8[n] = *(const bf16x8*)&omh[n * 16 + lr][kk * 32 + kg8];
                bl8[n] = *(const bf16x8*)&oml[n * 16 + lr][kk * 32 + kg8];
            }
            #pragma unroll
            for (int m = 0; m < 2; ++m)
                #pragma unroll
                for (int n = 0; n < 4; ++n) {
                    acc[m][n] = __builtin_amdgcn_mfma_f32_16x16x32_bf16(
                        a[m], bh8[n], acc[m][n], 0, 0, 0);
                    acc[m][n] = __builtin_amdgcn_mfma_f32_16x16x32_bf16(
                        a[m], bl8[n], acc[m][n], 0, 0, 0);
                }
        }
        __syncthreads();

        short (*kfT)[72] = zq;
        short (*vT)[72]  = zk;
        short (*Qrm)[72] = omh;
        short (*Krm)[72] = oml;
        {
            #pragma unroll
            for (int n = 0; n < 4; ++n) {
                const int f = n * 16 + lr;
                const float s_r   = (n < 2) ? s0 : s1;
                const float sq2s  = (n < 2) ? sq2s0 : sq2s1;
                const float scale = (n < 2) ? sc0 : sc1;
                #pragma unroll
                for (int m = 0; m < 2; ++m) {
                    const int tb4 = half * 32 + m * 16 + G * 4;
                    #pragma unroll
                    for (int j = 0; j < 4; ++j) {
                        const int t = tb4 + j;
                        const float proj = acc[m][n][j] * invn[p][t];
                        const float arg = fminf(fmaxf(proj * sq2s - s_r, -20.0f), 20.0f);
                        const float val = proj * proj * __expf(arg) * scale;
                        const short vb  = f2bf(val);
                        if (p == 0) { Qrm[t][f] = vb; }
                        else        { kfT[f][t] = vb; Krm[t][f] = vb; }
                    }
                }
            }
        }
        {
            const int row = tid >> 2;
            const int c0  = (tid & 3) * 16;
            const short* vrow = qkvb + ((size_t)(b * T_ + t0 + row)) * THREEC
                              + 2 * EMBED + h * HD;
            bf16x8 v0 = *(const bf16x8*)&vrow[c0], v1 = *(const bf16x8*)&vrow[c0 + 8];
            #pragma unroll
            for (int j = 0; j < 8; ++j) {
                vT[c0 + j][row]     = v0[j];
                vT[c0 + 8 + j][row] = v1[j];
            }
        }
        __syncthreads();

        // QK^T for own 16-row band; retain Q fragments
        bf16x8 aqq[2];
        aqq[0] = *(const bf16x8*)&Qrm[r0 + lr][kg8];
        aqq[1] = *(const bf16x8*)&Qrm[r0 + lr][32 + kg8];
        if (cc == 0) { aqR0[0] = aqq[0]; aqR0[1] = aqq[1]; }
        else         { aqR1[0] = aqq[0]; aqR1[1] = aqq[1]; }
        f32x4 accA[4] = {};
        #pragma unroll
        for (int n = 0; n < 4; ++n) {
            accA[n] = __builtin_amdgcn_mfma_f32_16x16x32_bf16(
                aqq[0], *(const bf16x8*)&Krm[n * 16 + lr][kg8], accA[n], 0, 0, 0);
            accA[n] = __builtin_amdgcn_mfma_f32_16x16x32_bf16(
                aqq[1], *(const bf16x8*)&Krm[n * 16 + lr][32 + kg8], accA[n], 0, 0, 0);
        }
        {
            float rsum[4] = {0.0f, 0.0f, 0.0f, 0.0f};
            #pragma unroll
            for (int n = 0; n < 4; ++n) {
                const int s = n * 16 + lr;
                #pragma unroll
                for (int j = 0; j < 4; ++j) {
                    const int t = r0 + G * 4 + j;
                    if (s <= t) rsum[j] += accA[n][j];
                }
            }
            #pragma unroll
            for (int j = 0; j < 4; ++j) {
                rsum[j] += __shfl_xor(rsum[j], 1, 64);
                rsum[j] += __shfl_xor(rsum[j], 2, 64);
                rsum[j] += __shfl_xor(rsum[j], 4, 64);
                rsum[j] += __shfl_xor(rsum[j], 8, 64);
            }
            if (cc == 0) { rsR0[0]=rsum[0]; rsR0[1]=rsum[1]; rsR0[2]=rsum[2]; rsR0[3]=rsum[3]; }
            else         { rsR1[0]=rsum[0]; rsR1[1]=rsum[1]; rsR1[2]=rsum[2]; rsR1[3]=rsum[3]; }
        }
        // chunk sums S[f][d] -> cKVb (bf16, [chunk][d][f]); cK sums
        {
            bf16x8 a2[2];
            a2[0] = *(const bf16x8*)&kfT[wave * 16 + lr][kg8];
            a2[1] = *(const bf16x8*)&kfT[wave * 16 + lr][32 + kg8];
            f32x4 sa[4] = {};
            #pragma unroll
            for (int n = 0; n < 4; ++n) {
                sa[n] = __builtin_amdgcn_mfma_f32_16x16x32_bf16(
                    a2[0], *(const bf16x8*)&vT[n * 16 + lr][kg8], sa[n], 0, 0, 0);
                sa[n] = __builtin_amdgcn_mfma_f32_16x16x32_bf16(
                    a2[1], *(const bf16x8*)&vT[n * 16 + lr][32 + kg8], sa[n], 0, 0, 0);
            }
            short* basep = cKVb + (size_t)chunk * (NFEAT * HD);
            #pragma unroll
            for (int n = 0; n < 4; ++n) {
                bf16x4 o = { f2bf(sa[n][0]), f2bf(sa[n][1]),
                             f2bf(sa[n][2]), f2bf(sa[n][3]) };
                *(bf16x4*)&basep[(n * 16 + lr) * NFEAT + wave * 16 + G * 4] = o;
            }
        }
        {
            const int f  = tid >> 2;
            const int tq = tid & 3;
            float s = 0.0f;
            #pragma unroll
            for (int j = 0; j < 16; ++j) s += bf2f(kfT[f][tq * 16 + j]);
            s += __shfl_xor(s, 1, 64);
            s += __shfl_xor(s, 2, 64);
            if (tq == 0) cK[(size_t)chunk * NFEAT + f] = s;
        }
        __syncthreads();   // Krm reads done -> oml reusable as At

        short (*At)[72] = oml;
        #pragma unroll
        for (int n = 0; n < 4; ++n) {
            const int s = n * 16 + lr;
            #pragma unroll
            for (int j = 0; j < 4; ++j) {
                const int t = r0 + G * 4 + j;
                At[t][s] = f2bf((s <= t) ? accA[n][j] : 0.0f);
            }
        }
        __syncthreads();
        {
            bf16x8 aa[2];
            aa[0] = *(const bf16x8*)&At[r0 + lr][kg8];
            aa[1] = *(const bf16x8*)&At[r0 + lr][32 + kg8];
            f32x4 a2[4] = {};
            #pragma unroll
            for (int n = 0; n < 4; ++n) {
                a2[n] = __builtin_amdgcn_mfma_f32_16x16x32_bf16(
                    aa[0], *(const bf16x8*)&vT[n * 16 + lr][kg8], a2[n], 0, 0, 0);
                a2[n] = __builtin_amdgcn_mfma_f32_16x16x32_bf16(
                    aa[1], *(const bf16x8*)&vT[n * 16 + lr][32 + kg8], a2[n], 0, 0, 0);
            }
            __syncthreads();   // At MFMA reads done before rewrite as ctx rows
            #pragma unroll
            for (int n = 0; n < 4; ++n) {
                const int d = n * 16 + lr;
                #pragma unroll
                for (int j = 0; j < 4; ++j) {
                    const int t = r0 + G * 4 + j;
                    At[t][d] = f2bf(a2[n][j]);
                }
            }
        }
        __syncthreads();
        {
            const int row = tid >> 2;
            const int c0  = (tid & 3) * 16;
            short* dst = ctxb + ((size_t)bh * T_ + t0 + row) * NFEAT;
            *(bf16x8*)&dst[c0]     = *(const bf16x8*)&At[row][c0];
            *(bf16x8*)&dst[c0 + 8] = *(const bf16x8*)&At[row][c0 + 8];
        }
    }

    __threadfence();
    cg::this_grid().sync();

    // ------------------------- phase B: prefix --------------------------
    if (g < 128) {
        const int bh = g >> 2;
        const int sl = g & 3;
        short* base = cKVb + (size_t)bh * NC_ * (NFEAT * HD) + sl * 1024 + tid * 4;
        bf16x4 n0 = *(const bf16x4*)(base);
        bf16x4 n1 = *(const bf16x4*)(base + 4096);
        float pref[4] = {0.0f, 0.0f, 0.0f, 0.0f};
        for (int c = 0; c < NC_; ++c) {
            bf16x4 cur = n0;
            n0 = n1;
            if (c + 2 < NC_) n1 = *(const bf16x4*)(base + (size_t)(c + 2) * 4096);
            else { n1[0] = 0; n1[1] = 0; n1[2] = 0; n1[3] = 0; }
            bf16x4 o = { f2bf(pref[0]), f2bf(pref[1]), f2bf(pref[2]), f2bf(pref[3]) };
            *(bf16x4*)(base + (size_t)c * 4096) = o;
            pref[0] += bf2f(cur[0]); pref[1] += bf2f(cur[1]);
            pref[2] += bf2f(cur[2]); pref[3] += bf2f(cur[3]);
        }
        if (sl == 0 && tid < 64) {
            float* kb = cK + (size_t)bh * NC_ * NFEAT + tid;
            float m0 = kb[0];
            float m1 = kb[64];
            float pp = 0.0f;
            for (int c = 0; c < NC_; ++c) {
                float cu = m0;
                m0 = m1;
                m1 = (c + 2 < NC_) ? kb[(size_t)(c + 2) * 64] : 0.0f;
                kb[(size_t)c * 64] = pp;
                pp += cu;
            }
        }
    }

    __threadfence();
    cg::this_grid().sync();
    __threadfence();   // acquire: invalidate stale L2 lines before phase C reads

    // ------------------------- phase C: inter ---------------------------
    #pragma unroll
    for (int cc = 0; cc < 2; ++cc) {
        const int chunk = 2 * g + cc;
        const int bh = chunk >> 6, c = chunk & 63;
        const int b = bh >> 4, h = bh & 15;
        const int t0 = c * 64;
        __syncthreads();
        {
            const int row = tid >> 2;
            const int c0  = (tid & 3) * 16;
            const short* prow = cKVb + (size_t)chunk * (NFEAT * HD) + row * NFEAT;
            const short* crow = ctxb + ((size_t)bh * T_ + t0 + row) * NFEAT;
            *(bf16x8*)&zq[row][c0]     = *(const bf16x8*)&prow[c0];   // Pp [d][f]
            *(bf16x8*)&zq[row][c0 + 8] = *(const bf16x8*)&prow[c0 + 8];
            *(bf16x8*)&zk[row][c0]     = *(const bf16x8*)&crow[c0];   // Ct [t][d]
            *(bf16x8*)&zk[row][c0 + 8] = *(const bf16x8*)&crow[c0 + 8];
            if (tid < 64) invn[0][tid] = cK[(size_t)chunk * NFEAT + tid];
        }
        __syncthreads();

        const bf16x8 aq0 = cc ? aqR1[0] : aqR0[0];
        const bf16x8 aq1 = cc ? aqR1[1] : aqR0[1];
        const float  rsv0 = cc ? rsR1[0] : rsR0[0];
        const float  rsv1 = cc ? rsR1[1] : rsR0[1];
        const float  rsv2 = cc ? rsR1[2] : rsR0[2];
        const float  rsv3 = cc ? rsR1[3] : rsR0[3];

        // qkp[t] via MFMA: B column 0 = cKp
        bf16x8 b0 = {0,0,0,0,0,0,0,0}, b1 = {0,0,0,0,0,0,0,0};
        if (lr == 0) {
            #pragma unroll
            for (int j = 0; j < 8; ++j) {
                b0[j] = f2bf(invn[0][kg8 + j]);
                b1[j] = f2bf(invn[0][32 + kg8 + j]);
            }
        }
        f32x4 qk = {};
        qk = __builtin_amdgcn_mfma_f32_16x16x32_bf16(aq0, b0, qk, 0, 0, 0);
        qk = __builtin_amdgcn_mfma_f32_16x16x32_bf16(aq1, b1, qk, 0, 0, 0);
        float qkp[4];
        #pragma unroll
        for (int j = 0; j < 4; ++j) qkp[j] = __shfl(qk[j], lane & 48, 64);

        f32x4 acc[4] = {};
        #pragma unroll
        for (int n = 0; n < 4; ++n) {
            acc[n] = __builtin_amdgcn_mfma_f32_16x16x32_bf16(
                aq0, *(const bf16x8*)&zq[n * 16 + lr][kg8], acc[n], 0, 0, 0);
            acc[n] = __builtin_amdgcn_mfma_f32_16x16x32_bf16(
                aq1, *(const bf16x8*)&zq[n * 16 + lr][32 + kg8], acc[n], 0, 0, 0);
        }

        const float rsv[4] = {rsv0, rsv1, rsv2, rsv3};
        float inv[4];
        #pragma unroll
        for (int j = 0; j < 4; ++j)
            inv[j] = 1.0f / fmaxf(rsv[j] + qkp[j], 1e-6f);
        #pragma unroll
        for (int n = 0; n < 4; ++n) {
            const int d = n * 16 + lr;
            #pragma unroll
            for (int j = 0; j < 4; ++j) {
                const int t = r0 + G * 4 + j;
                attnb[((size_t)(b * T_ + t0 + t)) * EMBED + h * HD + d] =
                    f2bf((bf2f(zk[t][d]) + acc[n][j]) * inv[j]);
            }
        }
    }
}

// ===========================================================================
// Fallback (round-10) kernels: feat_fused / prefix_scan / inter_attn
// ===========================================================================
__global__ __launch_bounds__(256) void feat_fused(
    const short* __restrict__ qkvb,
    const short* __restrict__ omgH,
    const short* __restrict__ omgL,
    const float* __restrict__ qn,
    const float* __restrict__ qw,
    short* __restrict__ qf,
    short* __restrict__ ctxb,
    float* __restrict__ rs_g,
    short* __restrict__ cKVb,
    float* __restrict__ cK)
{
    __shared__ short zq[64][72];
    __shared__ short zk[64][72];
    __shared__ short omh[64][72];
    __shared__ short oml[64][72];
    __shared__ float invn[2][64];
    __shared__ float rs_l[64];

    const int tid   = threadIdx.x;
    const int chunk = blockIdx.x;
    const int bh    = chunk >> 6;
    const int c     = chunk & 63;
    const int b     = bh >> 4, h = bh & 15;
    const int t0    = c * 64;

    {
        const int row = tid >> 2;
        const int c0  = (tid & 3) * 16;
        const size_t zbase = ((size_t)(b * T_ + t0 + row)) * THREEC + h * HD + c0;
        const size_t obase = ((size_t)h * NFEAT + row) * HD + c0;
        *(bf16x8*)&zq[row][c0]      = *(const bf16x8*)&qkvb[zbase];
        *(bf16x8*)&zq[row][c0 + 8]  = *(const bf16x8*)&qkvb[zbase + 8];
        *(bf16x8*)&zk[row][c0]      = *(const bf16x8*)&qkvb[zbase + EMBED];
        *(bf16x8*)&zk[row][c0 + 8]  = *(const bf16x8*)&qkvb[zbase + EMBED + 8];
        *(bf16x8*)&omh[row][c0]     = *(const bf16x8*)&omgH[obase];
        *(bf16x8*)&omh[row][c0 + 8] = *(const bf16x8*)&omgH[obase + 8];
        *(bf16x8*)&oml[row][c0]     = *(const bf16x8*)&omgL[obase];
        *(bf16x8*)&oml[row][c0 + 8] = *(const bf16x8*)&omgL[obase + 8];
    }
    __syncthreads();

    {
        const int t = tid >> 2;
        const int q = tid & 3;
        #pragma unroll
        for (int p = 0; p < 2; ++p) {
            const short* Z = p ? &zk[t][q * 16] : &zq[t][q * 16];
            float ss = 0.0f;
            #pragma unroll
            for (int j = 0; j < 16; ++j) { float v = bf2f(Z[j]); ss += v * v; }
            ss += __shfl_xor(ss, 1, 64);
            ss += __shfl_xor(ss, 2, 64);
            if (q == 0) invn[p][t] = 1.0f / fmaxf(sqrtf(ss), 1e-12f);
        }
    }
    __syncthreads();

    const int wave = tid >> 6;
    const int lane = tid & 63;
    const int p    = wave >> 1;
    const int half = wave & 1;
    const short (*Z)[72] = p ? zk : zq;

    const float s0 = qn[0], s1 = qn[1];
    const float sq2s0 = sqrtf(2.0f * fmaxf(s0, 0.0f));
    const float sq2s1 = sqrtf(2.0f * fmaxf(s1, 0.0f));
    const float sc0 = sqrtf(fmaxf(qw[0], 0.0f)) * (1.0f / 32.0f);
    const float sc1 = sqrtf(fmaxf(qw[1], 0.0f)) * (1.0f / 32.0f);

    const int lr  = lane & 15;
    const int G   = lane >> 4;
    const int kg8 = G * 8;

    f32x4 acc[2][4] = {};
    #pragma unroll
    for (int kk = 0; kk < 2; ++kk) {
        bf16x8 a[2], bh8[4], bl8[4];
        #pragma unroll
        for (int m = 0; m < 2; ++m)
            a[m] = *(const bf16x8*)&Z[half * 32 + m * 16 + lr][kk * 32 + kg8];
        #pragma unroll
        for (int n = 0; n < 4; ++n) {
            bh8[n] = *(const bf16x8*)&omh[n * 16 + lr][kk * 32 + kg8];
            bl8[n] = *(const bf16x8*)&oml[n * 16 + lr][kk * 32 + kg8];
        }
        #pragma unroll
        for (int m = 0; m < 2; ++m)
            #pragma unroll
            for (int n = 0; n < 4; ++n) {
                acc[m][n] = __builtin_amdgcn_mfma_f32_16x16x32_bf16(
                    a[m], bh8[n], acc[m][n], 0, 0, 0);
                acc[m][n] = __builtin_amdgcn_mfma_f32_16x16x32_bf16(
                    a[m], bl8[n], acc[m][n], 0, 0, 0);
            }
    }
    __syncthreads();

    short (*kfT)[72] = zq;
    short (*vT)[72]  = zk;
    short (*Qrm)[72] = omh;
    short (*Krm)[72] = oml;
    {
        #pragma unroll
        for (int n = 0; n < 4; ++n) {
            const int f = n * 16 + lr;
            const float s_r   = (n < 2) ? s0 : s1;
            const float sq2s  = (n < 2) ? sq2s0 : sq2s1;
            const float scale = (n < 2) ? sc0 : sc1;
            #pragma unroll
            for (int m = 0; m < 2; ++m) {
                const int tb4 = half * 32 + m * 16 + G * 4;
                #pragma unroll
                for (int j = 0; j < 4; ++j) {
                    const int t = tb4 + j;
                    const float proj = acc[m][n][j] * invn[p][t];
                    const float arg = fminf(fmaxf(proj * sq2s - s_r, -20.0f), 20.0f);
                    const float val = proj * proj * __expf(arg) * scale;
                    const short vb  = f2bf(val);
                    if (p == 0) { Qrm[t][f] = vb; }
                    else        { kfT[f][t] = vb; Krm[t][f] = vb; }
                }
            }
        }
    }
    {
        const int row = tid >> 2;
        const int c0  = (tid & 3) * 16;
        const short* vrow = qkvb + ((size_t)(b * T_ + t0 + row)) * THREEC
                          + 2 * EMBED + h * HD;
        bf16x8 v0 = *(const bf16x8*)&vrow[c0], v1 = *(const bf16x8*)&vrow[c0 + 8];
        #pragma unroll
        for (int j = 0; j < 8; ++j) {
            vT[c0 + j][row]     = v0[j];
            vT[c0 + 8 + j][row] = v1[j];
        }
    }
    __syncthreads();

    const int r0 = wave * 16;

    {
        const int row = tid >> 2;
        const int c0  = (tid & 3) * 16;
        short* dst = qf + ((size_t)bh * T_ + t0 + row) * NFEAT;
        *(bf16x8*)&dst[c0]     = *(const bf16x8*)&Qrm[row][c0];
        *(bf16x8*)&dst[c0 + 8] = *(const bf16x8*)&Qrm[row][c0 + 8];
    }
    bf16x8 aqq[2];
    aqq[0] = *(const bf16x8*)&Qrm[r0 + lr][kg8];
    aqq[1] = *(const bf16x8*)&Qrm[r0 + lr][32 + kg8];
    f32x4 accA[4] = {};
    #pragma unroll
    for (int n = 0; n < 4; ++n) {
        accA[n] = __builtin_amdgcn_mfma_f32_16x16x32_bf16(
            aqq[0], *(const bf16x8*)&Krm[n * 16 + lr][kg8], accA[n], 0, 0, 0);
        accA[n] = __builtin_amdgcn_mfma_f32_16x16x32_bf16(
            aqq[1], *(const bf16x8*)&Krm[n * 16 + lr][32 + kg8], accA[n], 0, 0, 0);
    }
    {
        float rsum[4] = {0.0f, 0.0f, 0.0f, 0.0f};
        #pragma unroll
        for (int n = 0; n < 4; ++n) {
            const int s = n * 16 + lr;
            #pragma unroll
            for (int j = 0; j < 4; ++j) {
                const int t = r0 + G * 4 + j;
                if (s <= t) rsum[j] += accA[n][j];
            }
        }
        #pragma unroll
        for (int j = 0; j < 4; ++j) {
            rsum[j] += __shfl_xor(rsum[j], 1, 64);
            rsum[j] += __shfl_xor(rsum[j], 2, 64);
            rsum[j] += __shfl_xor(rsum[j], 4, 64);
            rsum[j] += __shfl_xor(rsum[j], 8, 64);
        }
        if (lr == 0) {
            #pragma unroll
            for (int j = 0; j < 4; ++j) rs_l[r0 + G * 4 + j] = rsum[j];
        }
    }
    {
        bf16x8 a2[2];
        a2[0] = *(const bf16x8*)&kfT[wave * 16 + lr][kg8];
        a2[1] = *(const bf16x8*)&kfT[wave * 16 + lr][32 + kg8];
        f32x4 sa[4] = {};
        #pragma unroll
        for (int n = 0; n < 4; ++n) {
            sa[n] = __builtin_amdgcn_mfma_f32_16x16x32_bf16(
                a2[0], *(const bf16x8*)&vT[n * 16 + lr][kg8], sa[n], 0, 0, 0);
            sa[n] = __builtin_amdgcn_mfma_f32_16x16x32_bf16(
                a2[1], *(const bf16x8*)&vT[n * 16 + lr][32 + kg8], sa[n], 0, 0, 0);
        }
        short* basep = cKVb + (size_t)chunk * (NFEAT * HD);
        #pragma unroll
        for (int n = 0; n < 4; ++n) {
            bf16x4 o = { f2bf(sa[n][0]), f2bf(sa[n][1]),
                         f2bf(sa[n][2]), f2bf(sa[n][3]) };
            *(bf16x4*)&basep[(n * 16 + lr) * NFEAT + wave * 16 + G * 4] = o;
        }
    }
    {
        const int f  = tid >> 2;
        const int tq = tid & 3;
        float s = 0.0f;
        #pragma unroll
        for (int j = 0; j < 16; ++j) s += bf2f(kfT[f][tq * 16 + j]);
        s += __shfl_xor(s, 1, 64);
        s += __shfl_xor(s, 2, 64);
        if (tq == 0) cK[(size_t)chunk * NFEAT + f] = s;
    }
    __syncthreads();

    short (*At)[72] = oml;
    #pragma unroll
    for (int n = 0; n < 4; ++n) {
        const int s = n * 16 + lr;
        #pragma unroll
        for (int j = 0; j < 4; ++j) {
            const int t = r0 + G * 4 + j;
            At[t][s] = f2bf((s <= t) ? accA[n][j] : 0.0f);
        }
    }
    __syncthreads();

    {
        bf16x8 aa[2];
        aa[0] = *(const bf16x8*)&At[r0 + lr][kg8];
        aa[1] = *(const bf16x8*)&At[r0 + lr][32 + kg8];
        f32x4 a2[4] = {};
        #pragma unroll
        for (int n = 0; n < 4; ++n) {
            a2[n] = __builtin_amdgcn_mfma_f32_16x16x32_bf16(
                aa[0], *(const bf16x8*)&vT[n * 16 + lr][kg8], a2[n], 0, 0, 0);
            a2[n] = __builtin_amdgcn_mfma_f32_16x16x32_bf16(
                aa[1], *(const bf16x8*)&vT[n * 16 + lr][32 + kg8], a2[n], 0, 0, 0);
        }
        __syncthreads();
        #pragma unroll
        for (int n = 0; n < 4; ++n) {
            const int d = n * 16 + lr;
            #pragma unroll
            for (int j = 0; j < 4; ++j) {
                const int t = r0 + G * 4 + j;
                At[t][d] = f2bf(a2[n][j]);
            }
        }
    }
    __syncthreads();
    {
        const int row = tid >> 2;
        const int c0  = (tid & 3) * 16;
        short* dst = ctxb + ((size_t)bh * T_ + t0 + row) * NFEAT;
        *(bf16x8*)&dst[c0]     = *(const bf16x8*)&At[row][c0];
        *(bf16x8*)&dst[c0 + 8] = *(const bf16x8*)&At[row][c0 + 8];
    }
    if (tid < 64) rs_g[(size_t)bh * T_ + t0 + tid] = rs_l[tid];
}

__global__ __launch_bounds__(256) void prefix_scan(
    short* __restrict__ cKVb, float* __restrict__ cK)
{
    const int bh  = blockIdx.x >> 2;
    const int sl  = blockIdx.x & 3;
    const int tid = threadIdx.x;
    short* base = cKVb + (size_t)bh * NC_ * (NFEAT * HD) + sl * 1024 + tid * 4;
    bf16x4 n0 = *(const bf16x4*)(base);
    bf16x4 n1 = *(const bf16x4*)(base + 4096);
    float pref[4] = {0.0f, 0.0f, 0.0f, 0.0f};
    for (int c = 0; c < NC_; ++c) {
        bf16x4 cur = n0;
        n0 = n1;
        if (c + 2 < NC_) n1 = *(const bf16x4*)(base + (size_t)(c + 2) * 4096);
        else { n1[0] = 0; n1[1] = 0; n1[2] = 0; n1[3] = 0; }
        bf16x4 o = { f2bf(pref[0]), f2bf(pref[1]), f2bf(pref[2]), f2bf(pref[3]) };
        *(bf16x4*)(base + (size_t)c * 4096) = o;
        pref[0] += bf2f(cur[0]); pref[1] += bf2f(cur[1]);
        pref[2] += bf2f(cur[2]); pref[3] += bf2f(cur[3]);
    }
    if (sl == 0 && tid < 64) {
        float* kb = cK + (size_t)bh * NC_ * NFEAT + tid;
        float m0 = kb[0];
        float m1 = kb[64];
        float p = 0.0f;
        for (int c = 0; c < NC_; ++c) {
            float cu = m0;
            m0 = m1;
            m1 = (c + 2 < NC_) ? kb[(size_t)(c + 2) * 64] : 0.0f;
            kb[(size_t)c * 64] = p;
            p += cu;
        }
    }
}

__global__ __launch_bounds__(256) void inter_attn(
    const short* __restrict__ qf,
    const short* __restrict__ ctxb,
    const float* __restrict__ rs_g,
    const short* __restrict__ cKVp,
    const float* __restrict__ cKp_g,
    short* __restrict__ attnb)
{
    __shared__ short Q[64][72];
    __shared__ short Pp[64][72];
    __shared__ short Ct[64][72];
    __shared__ float cKp[64], rs[64], qkp_l[64];

    const int tid = threadIdx.x;
    const int chunk = blockIdx.x;
    const int bh = chunk >> 6, c = chunk & 63;
    const int b = bh >> 4, h = bh & 15;
    const int t0 = c * 64;

    {
        const int row = tid >> 2;
        const int c0  = (tid & 3) * 16;
        const short* qrow = qf   + ((size_t)bh * T_ + t0 + row) * NFEAT;
        const short* crow = ctxb + ((size_t)bh * T_ + t0 + row) * NFEAT;
        const short* prow = cKVp + (size_t)chunk * (NFEAT * HD) + row * NFEAT;
        *(bf16x8*)&Q[row][c0]      = *(const bf16x8*)&qrow[c0];
        *(bf16x8*)&Q[row][c0 + 8]  = *(const bf16x8*)&qrow[c0 + 8];
        *(bf16x8*)&Ct[row][c0]     = *(const bf16x8*)&crow[c0];
        *(bf16x8*)&Ct[row][c0 + 8] = *(const bf16x8*)&crow[c0 + 8];
        *(bf16x8*)&Pp[row][c0]     = *(const bf16x8*)&prow[c0];
        *(bf16x8*)&Pp[row][c0 + 8] = *(const bf16x8*)&prow[c0 + 8];
        if (tid < 64) {
            cKp[tid] = cKp_g[(size_t)chunk * NFEAT + tid];
            rs[tid]  = rs_g[(size_t)bh * T_ + t0 + tid];
        }
    }
    __syncthreads();

    {
        const int t  = tid >> 2;
        const int fq = (tid & 3) * 16;
        float s = 0.0f;
        #pragma unroll
        for (int j = 0; j < 16; ++j) s += bf2f(Q[t][fq + j]) * cKp[fq + j];
        s += __shfl_xor(s, 1, 64);
        s += __shfl_xor(s, 2, 64);
        if ((tid & 3) == 0) qkp_l[t] = s;
    }

    const int wave = tid >> 6;
    const int lane = tid & 63;
    const int lr = lane & 15;
    const int G  = lane >> 4;
    const int kg = G * 8;
    const int r0 = wave * 16;

    bf16x8 aq[2];
    aq[0] = *(const bf16x8*)&Q[r0 + lr][kg];
    aq[1] = *(const bf16x8*)&Q[r0 + lr][32 + kg];
    f32x4 acc[4] = {};
    #pragma unroll
    for (int n = 0; n < 4; ++n) {
        acc[n] = __builtin_amdgcn_mfma_f32_16x16x32_bf16(
            aq[0], *(const bf16x8*)&Pp[n * 16 + lr][kg], acc[n], 0, 0, 0);
        acc[n] = __builtin_amdgcn_mfma_f32_16x16x32_bf16(
            aq[1], *(const bf16x8*)&Pp[n * 16 + lr][32 + kg], acc[n], 0, 0, 0);
    }
    __syncthreads();

    float inv[4];
    #pragma unroll
    for (int j = 0; j < 4; ++j) {
        const int t = r0 + G * 4 + j;
        inv[j] = 1.0f / fmaxf(rs[t] + qkp_l[t], 1e-6f);
    }
    #pragma unroll
    for (int n = 0; n < 4; ++n) {
        const int d = n * 16 + lr;
        #pragma unroll
        for (int j = 0; j < 4; ++j) {
            const int t = r0 + G * 4 + j;
            const float ctx = bf2f(Ct[t][d]);
            attnb[((size_t)(b * T_ + t0 + t)) * EMBED + h * HD + d] =
                f2bf((ctx + acc[n][j]) * inv[j]);
        }
    }
}

// ---------------------------------------------------------------------------
extern "C" void kernel_launch(void* const* d_in, const int* in_sizes, int n_in,
                              void* d_out, int out_size, void* d_ws, size_t ws_size,
                              hipStream_t stream)
{
    const float* x     = (const float*)d_in[0];
    const float* w_qkv = (const float*)d_in[1];
    const float* b_qkv = (const float*)d_in[2];
    const float* w_out = (const float*)d_in[3];
    const float* b_out = (const float*)d_in[4];
    const float* omega = (const float*)d_in[5];
    const float* qn    = (const float*)d_in[6];
    const float* qw    = (const float*)d_in[7];
    float* out = (float*)d_out;

    short* xb    = (short*)d_ws;               //  8,388,608
    short* wqb   = xb    + 8388608;            //  3,145,728
    short* wob   = wqb   + 3145728;            //  1,048,576
    short* qkvb  = wob   + 1048576;            // 25,165,824
    short* attnb = qkvb  + 25165824;           //  8,388,608
    short* omgH  = attnb + 8388608;            //     65,536
    short* omgL  = omgH  + 65536;              //     65,536
    short* qfb   = omgL  + 65536;              //  8,388,608
    short* ctxb  = qfb   + 8388608;            //  8,388,608
    short* cKVb  = ctxb  + 8388608;            //  8,388,608
    float* cK    = (float*)(cKVb + 8388608);   //    131,072 floats
    float* rs_g  = cK + 131072;                //    131,072 floats

    const int M = B_ * T_;   // 8192

    prep_kernel<<<dim3((NV_ALL + 65536) / 256), 256, 0, stream>>>(
        x, w_qkv, w_out, omega, xb, wqb, wob, omgH, omgL);

    gemm_bf16<1><<<dim3((M / 128) * (THREEC / 128)), 256, 0, stream>>>(
        xb, wqb, b_qkv, nullptr, qkvb, M, THREEC, EMBED);

    // Attention tail: cooperative mega-kernel if it fits, else 3-kernel path.
    int maxB = 0;
    hipError_t qe = hipOccupancyMaxActiveBlocksPerMultiprocessor(
        &maxB, mega_attn, 256, 0);
    bool coop_ok = (qe == hipSuccess && maxB >= 4);
    if (coop_ok) {
        const short* a_qkvb = qkvb;
        const short* a_omgH = omgH;
        const short* a_omgL = omgL;
        const float* a_qn   = qn;
        const float* a_qw   = qw;
        short* a_ctxb  = ctxb;
        short* a_cKVb  = cKVb;
        float* a_cK    = cK;
        short* a_attnb = attnb;
        void* args[] = { (void*)&a_qkvb, (void*)&a_omgH, (void*)&a_omgL,
                         (void*)&a_qn, (void*)&a_qw, (void*)&a_ctxb,
                         (void*)&a_cKVb, (void*)&a_cK, (void*)&a_attnb };
        hipError_t le = hipLaunchCooperativeKernel(
            (void*)mega_attn, dim3(BH_ * NC_ / 2), dim3(256), args, 0, stream);
        if (le != hipSuccess) { (void)hipGetLastError(); coop_ok = false; }
    }
    if (!coop_ok) {
        feat_fused<<<dim3(BH_ * NC_), 256, 0, stream>>>(
            qkvb, omgH, omgL, qn, qw, qfb, ctxb, rs_g, cKVb, cK);
        prefix_scan<<<dim3(BH_ * 4), 256, 0, stream>>>(cKVb, cK);
        inter_attn<<<dim3(BH_ * NC_), 256, 0, stream>>>(
            qfb, ctxb, rs_g, cKVb, cK, attnb);
    }

    gemm_bf16<0><<<dim3((EMBED / 128) * (M / 128)), 256, 0, stream>>>(
        attnb, wob, b_out, out, nullptr, M, EMBED, EMBED);
}

// Round 12
// 169.038 us; speedup vs baseline: 1.0027x; 1.0027x over previous
//
#include <hip/hip_runtime.h>
#include <math.h>

#define EMBED   1024
#define THREEC  3072
#define NH      16
#define HD      64
#define NFEAT   64      // R * M = 2 * 32
#define RN      2
#define MM_     32
#define B_      2
#define T_      4096
#define L_      64      // chunk length
#define NC_     64      // T_ / L_
#define BH_     32      // B_ * NH

typedef __attribute__((ext_vector_type(8))) short bf16x8;
typedef __attribute__((ext_vector_type(4))) short bf16x4;
typedef __attribute__((ext_vector_type(4))) float f32x4;

__device__ __forceinline__ float bf2f(short s) {
    unsigned u = ((unsigned)(unsigned short)s) << 16;
    return __builtin_bit_cast(float, u);
}
__device__ __forceinline__ short f2bf(float f) {
    unsigned u = __builtin_bit_cast(unsigned, f);
    u += 0x7fff + ((u >> 16) & 1);
    return (short)(u >> 16);
}
__device__ __forceinline__ void gload16(const short* g, short* l) {
    __builtin_amdgcn_global_load_lds(
        (const __attribute__((address_space(1))) void*)g,
        (__attribute__((address_space(3))) void*)l, 16, 0, 0);
}

// ---------------------------------------------------------------------------
// Fused prep: f32->bf16 casts for x, w_qkv, w_out + omega hi/lo transpose.
// ---------------------------------------------------------------------------
#define NV_X   1048576            // 8388608 / 8
#define NV_WQ  393216             // 3145728 / 8
#define NV_WO  131072             // 1048576 / 8
#define NV_ALL (NV_X + NV_WQ + NV_WO)
__global__ __launch_bounds__(256) void prep_kernel(
    const float* __restrict__ x, const float* __restrict__ wq,
    const float* __restrict__ wo, const float* __restrict__ omega,
    short* __restrict__ xb, short* __restrict__ wqb, short* __restrict__ wob,
    short* __restrict__ omgH, short* __restrict__ omgL)
{
    int i = blockIdx.x * 256 + threadIdx.x;
    if (i < NV_ALL) {
        const float* src; short* dst; int k;
        if (i < NV_X)            { src = x;  dst = xb;  k = i; }
        else if (i < NV_X+NV_WQ) { src = wq; dst = wqb; k = i - NV_X; }
        else                     { src = wo; dst = wob; k = i - NV_X - NV_WQ; }
        const float4* p = (const float4*)src + (size_t)k * 2;
        float4 a = p[0], b = p[1];
        bf16x8 o = { f2bf(a.x), f2bf(a.y), f2bf(a.z), f2bf(a.w),
                     f2bf(b.x), f2bf(b.y), f2bf(b.z), f2bf(b.w) };
        *((bf16x8*)dst + k) = o;
    } else {
        int j = i - NV_ALL;               // 0..65535 over H*F*D
        if (j < NH * NFEAT * HD) {
            int d = j & 63;
            int f = (j >> 6) & 63;
            int h = j >> 12;
            int r = f >> 5, m = f & 31;
            float w = omega[(((size_t)(r * NH + h) * HD + d) * MM_) + m];
            short a = f2bf(w);
            omgH[j] = a;
            omgL[j] = f2bf(w - bf2f(a));
        }
    }
}

// ---------------------------------------------------------------------------
// bf16 MFMA GEMM (m97 structure), 1D grid + XCD-aware M-stripe swizzle.
// ---------------------------------------------------------------------------
template<int OUTBF>
__global__ __launch_bounds__(256) void gemm_bf16(
    const short* __restrict__ A,      // [M][K] bf16
    const short* __restrict__ W,      // [N][K] bf16
    const float* __restrict__ bias,   // [N]
    float* __restrict__ Cf, short* __restrict__ Cb,
    int M, int N, int K)
{
    __shared__ short lA[2][128 * 32];
    __shared__ short lB[2][128 * 32];
    const int tid  = threadIdx.x;
    const int nbn  = N >> 7;
    const int cpx  = gridDim.x >> 3;
    const int swz  = (blockIdx.x & 7) * cpx + (blockIdx.x >> 3);
    const int bm   = (swz / nbn) << 7;
    const int bn   = (swz % nbn) << 7;
    const int lane = tid & 63;
    const int wave = tid >> 6;
    const int row0 = (wave >> 1) * 64;
    const int col0 = (wave & 1) * 64;
    const int lr   = lane & 15;
    const int kg8  = (lane >> 4) * 8;

    f32x4 acc[4][4] = {};

#define STAGE(buf, k0)                                                        \
    {                                                                         \
        _Pragma("unroll")                                                     \
        for (int i = 0; i < 2; ++i) {                                         \
            int idx = i * 256 + tid;                                          \
            int row = idx >> 2, kq = (idx & 3) * 8;                           \
            gload16(&A[(size_t)(bm + row) * K + (k0) + kq], &lA[buf][idx * 8]); \
            gload16(&W[(size_t)(bn + row) * K + (k0) + kq], &lB[buf][idx * 8]); \
        }                                                                     \
    }

    const int KT = K >> 5;
    STAGE(0, 0);
    __syncthreads();
    int cur = 0;
    for (int kt = 0; kt < KT; ++kt) {
        if (kt + 1 < KT) STAGE(cur ^ 1, (kt + 1) * 32);
        const short* As = lA[cur];
        const short* Bs = lB[cur];
        bf16x8 af[4], bfr[4];
        #pragma unroll
        for (int m = 0; m < 4; ++m)
            af[m] = *(const bf16x8*)&As[(row0 + m * 16 + lr) * 32 + kg8];
        #pragma unroll
        for (int n = 0; n < 4; ++n)
            bfr[n] = *(const bf16x8*)&Bs[(col0 + n * 16 + lr) * 32 + kg8];
        #pragma unroll
        for (int m = 0; m < 4; ++m)
            #pragma unroll
            for (int n = 0; n < 4; ++n)
                acc[m][n] = __builtin_amdgcn_mfma_f32_16x16x32_bf16(
                    af[m], bfr[n], acc[m][n], 0, 0, 0);
        __syncthreads();
        cur ^= 1;
    }
#undef STAGE

    #pragma unroll
    for (int n = 0; n < 4; ++n) {
        const int col = bn + col0 + n * 16 + (lane & 15);
        const float bvv = bias[col];
        #pragma unroll
        for (int m = 0; m < 4; ++m) {
            const int rbase = bm + row0 + m * 16 + (lane >> 4) * 4;
            #pragma unroll
            for (int j = 0; j < 4; ++j) {
                const float v = acc[m][n][j] + bvv;
                if (OUTBF) Cb[(size_t)(rbase + j) * N + col] = f2bf(v);
                else       Cf[(size_t)(rbase + j) * N + col] = v;
            }
        }
    }
}

// ---------------------------------------------------------------------------
// Fused: feature map + per-chunk KV sums + INTRA-chunk attention local part.
// LDS reuse: zq->kfT, zk->vT, omh->Qrm, oml->Krm->At->ctx-rows.
// ---------------------------------------------------------------------------
__global__ __launch_bounds__(256) void feat_fused(
    const short* __restrict__ qkvb,
    const short* __restrict__ omgH,
    const short* __restrict__ omgL,
    const float* __restrict__ qn,
    const float* __restrict__ qw,
    short* __restrict__ qf,
    short* __restrict__ ctxb,
    float* __restrict__ rs_g,
    short* __restrict__ cKVb,
    float* __restrict__ cK)
{
    __shared__ short zq[64][72];
    __shared__ short zk[64][72];
    __shared__ short omh[64][72];
    __shared__ short oml[64][72];
    __shared__ float invn[2][64];
    __shared__ float rs_l[64];

    const int tid   = threadIdx.x;
    const int chunk = blockIdx.x;
    const int bh    = chunk >> 6;
    const int c     = chunk & 63;
    const int b     = bh >> 4, h = bh & 15;
    const int t0    = c * 64;

    {
        const int row = tid >> 2;
        const int c0  = (tid & 3) * 16;
        const size_t zbase = ((size_t)(b * T_ + t0 + row)) * THREEC + h * HD + c0;
        const size_t obase = ((size_t)h * NFEAT + row) * HD + c0;
        *(bf16x8*)&zq[row][c0]      = *(const bf16x8*)&qkvb[zbase];
        *(bf16x8*)&zq[row][c0 + 8]  = *(const bf16x8*)&qkvb[zbase + 8];
        *(bf16x8*)&zk[row][c0]      = *(const bf16x8*)&qkvb[zbase + EMBED];
        *(bf16x8*)&zk[row][c0 + 8]  = *(const bf16x8*)&qkvb[zbase + EMBED + 8];
        *(bf16x8*)&omh[row][c0]     = *(const bf16x8*)&omgH[obase];
        *(bf16x8*)&omh[row][c0 + 8] = *(const bf16x8*)&omgH[obase + 8];
        *(bf16x8*)&oml[row][c0]     = *(const bf16x8*)&omgL[obase];
        *(bf16x8*)&oml[row][c0 + 8] = *(const bf16x8*)&omgL[obase + 8];
    }
    __syncthreads();

    {
        const int t = tid >> 2;
        const int q = tid & 3;
        #pragma unroll
        for (int p = 0; p < 2; ++p) {
            const short* Z = p ? &zk[t][q * 16] : &zq[t][q * 16];
            float ss = 0.0f;
            #pragma unroll
            for (int j = 0; j < 16; ++j) { float v = bf2f(Z[j]); ss += v * v; }
            ss += __shfl_xor(ss, 1, 64);
            ss += __shfl_xor(ss, 2, 64);
            if (q == 0) invn[p][t] = 1.0f / fmaxf(sqrtf(ss), 1e-12f);
        }
    }
    __syncthreads();

    const int wave = tid >> 6;
    const int lane = tid & 63;
    const int p    = wave >> 1;
    const int half = wave & 1;
    const short (*Z)[72] = p ? zk : zq;

    const float s0 = qn[0], s1 = qn[1];
    const float sq2s0 = sqrtf(2.0f * fmaxf(s0, 0.0f));
    const float sq2s1 = sqrtf(2.0f * fmaxf(s1, 0.0f));
    const float sc0 = sqrtf(fmaxf(qw[0], 0.0f)) * (1.0f / 32.0f);
    const float sc1 = sqrtf(fmaxf(qw[1], 0.0f)) * (1.0f / 32.0f);

    const int lr  = lane & 15;
    const int G   = lane >> 4;
    const int kg8 = G * 8;

    f32x4 acc[2][4] = {};
    #pragma unroll
    for (int kk = 0; kk < 2; ++kk) {
        bf16x8 a[2], bh8[4], bl8[4];
        #pragma unroll
        for (int m = 0; m < 2; ++m)
            a[m] = *(const bf16x8*)&Z[half * 32 + m * 16 + lr][kk * 32 + kg8];
        #pragma unroll
        for (int n = 0; n < 4; ++n) {
            bh8[n] = *(const bf16x8*)&omh[n * 16 + lr][kk * 32 + kg8];
            bl8[n] = *(const bf16x8*)&oml[n * 16 + lr][kk * 32 + kg8];
        }
        #pragma unroll
        for (int m = 0; m < 2; ++m)
            #pragma unroll
            for (int n = 0; n < 4; ++n) {
                acc[m][n] = __builtin_amdgcn_mfma_f32_16x16x32_bf16(
                    a[m], bh8[n], acc[m][n], 0, 0, 0);
                acc[m][n] = __builtin_amdgcn_mfma_f32_16x16x32_bf16(
                    a[m], bl8[n], acc[m][n], 0, 0, 0);
            }
    }
    __syncthreads();

    short (*kfT)[72] = zq;
    short (*vT)[72]  = zk;
    short (*Qrm)[72] = omh;
    short (*Krm)[72] = oml;
    {
        #pragma unroll
        for (int n = 0; n < 4; ++n) {
            const int f = n * 16 + lr;
            const float s_r   = (n < 2) ? s0 : s1;
            const float sq2s  = (n < 2) ? sq2s0 : sq2s1;
            const float scale = (n < 2) ? sc0 : sc1;
            #pragma unroll
            for (int m = 0; m < 2; ++m) {
                const int tb4 = half * 32 + m * 16 + G * 4;
                #pragma unroll
                for (int j = 0; j < 4; ++j) {
                    const int t = tb4 + j;
                    const float proj = acc[m][n][j] * invn[p][t];
                    const float arg = fminf(fmaxf(proj * sq2s - s_r, -20.0f), 20.0f);
                    const float val = proj * proj * __expf(arg) * scale;
                    const short vb  = f2bf(val);
                    if (p == 0) { Qrm[t][f] = vb; }
                    else        { kfT[f][t] = vb; Krm[t][f] = vb; }
                }
            }
        }
    }
    {
        const int row = tid >> 2;
        const int c0  = (tid & 3) * 16;
        const short* vrow = qkvb + ((size_t)(b * T_ + t0 + row)) * THREEC
                          + 2 * EMBED + h * HD;
        bf16x8 v0 = *(const bf16x8*)&vrow[c0], v1 = *(const bf16x8*)&vrow[c0 + 8];
        #pragma unroll
        for (int j = 0; j < 8; ++j) {
            vT[c0 + j][row]     = v0[j];
            vT[c0 + 8 + j][row] = v1[j];
        }
    }
    __syncthreads();

    const int r0 = wave * 16;

    {
        const int row = tid >> 2;
        const int c0  = (tid & 3) * 16;
        short* dst = qf + ((size_t)bh * T_ + t0 + row) * NFEAT;
        *(bf16x8*)&dst[c0]     = *(const bf16x8*)&Qrm[row][c0];
        *(bf16x8*)&dst[c0 + 8] = *(const bf16x8*)&Qrm[row][c0 + 8];
    }
    bf16x8 aqq[2];
    aqq[0] = *(const bf16x8*)&Qrm[r0 + lr][kg8];
    aqq[1] = *(const bf16x8*)&Qrm[r0 + lr][32 + kg8];
    f32x4 accA[4] = {};
    #pragma unroll
    for (int n = 0; n < 4; ++n) {
        accA[n] = __builtin_amdgcn_mfma_f32_16x16x32_bf16(
            aqq[0], *(const bf16x8*)&Krm[n * 16 + lr][kg8], accA[n], 0, 0, 0);
        accA[n] = __builtin_amdgcn_mfma_f32_16x16x32_bf16(
            aqq[1], *(const bf16x8*)&Krm[n * 16 + lr][32 + kg8], accA[n], 0, 0, 0);
    }
    {
        float rsum[4] = {0.0f, 0.0f, 0.0f, 0.0f};
        #pragma unroll
        for (int n = 0; n < 4; ++n) {
            const int s = n * 16 + lr;
            #pragma unroll
            for (int j = 0; j < 4; ++j) {
                const int t = r0 + G * 4 + j;
                if (s <= t) rsum[j] += accA[n][j];
            }
        }
        #pragma unroll
        for (int j = 0; j < 4; ++j) {
            rsum[j] += __shfl_xor(rsum[j], 1, 64);
            rsum[j] += __shfl_xor(rsum[j], 2, 64);
            rsum[j] += __shfl_xor(rsum[j], 4, 64);
            rsum[j] += __shfl_xor(rsum[j], 8, 64);
        }
        if (lr == 0) {
            #pragma unroll
            for (int j = 0; j < 4; ++j) rs_l[r0 + G * 4 + j] = rsum[j];
        }
    }
    {
        bf16x8 a2[2];
        a2[0] = *(const bf16x8*)&kfT[wave * 16 + lr][kg8];
        a2[1] = *(const bf16x8*)&kfT[wave * 16 + lr][32 + kg8];
        f32x4 sa[4] = {};
        #pragma unroll
        for (int n = 0; n < 4; ++n) {
            sa[n] = __builtin_amdgcn_mfma_f32_16x16x32_bf16(
                a2[0], *(const bf16x8*)&vT[n * 16 + lr][kg8], sa[n], 0, 0, 0);
            sa[n] = __builtin_amdgcn_mfma_f32_16x16x32_bf16(
                a2[1], *(const bf16x8*)&vT[n * 16 + lr][32 + kg8], sa[n], 0, 0, 0);
        }
        short* basep = cKVb + (size_t)chunk * (NFEAT * HD);
        #pragma unroll
        for (int n = 0; n < 4; ++n) {
            bf16x4 o = { f2bf(sa[n][0]), f2bf(sa[n][1]),
                         f2bf(sa[n][2]), f2bf(sa[n][3]) };
            *(bf16x4*)&basep[(n * 16 + lr) * NFEAT + wave * 16 + G * 4] = o;
        }
    }
    {
        const int f  = tid >> 2;
        const int tq = tid & 3;
        float s = 0.0f;
        #pragma unroll
        for (int j = 0; j < 16; ++j) s += bf2f(kfT[f][tq * 16 + j]);
        s += __shfl_xor(s, 1, 64);
        s += __shfl_xor(s, 2, 64);
        if (tq == 0) cK[(size_t)chunk * NFEAT + f] = s;
    }
    __syncthreads();

    short (*At)[72] = oml;
    #pragma unroll
    for (int n = 0; n < 4; ++n) {
        const int s = n * 16 + lr;
        #pragma unroll
        for (int j = 0; j < 4; ++j) {
            const int t = r0 + G * 4 + j;
            At[t][s] = f2bf((s <= t) ? accA[n][j] : 0.0f);
        }
    }
    __syncthreads();

    {
        bf16x8 aa[2];
        aa[0] = *(const bf16x8*)&At[r0 + lr][kg8];
        aa[1] = *(const bf16x8*)&At[r0 + lr][32 + kg8];
        f32x4 a2[4] = {};
        #pragma unroll
        for (int n = 0; n < 4; ++n) {
            a2[n] = __builtin_amdgcn_mfma_f32_16x16x32_bf16(
                aa[0], *(const bf16x8*)&vT[n * 16 + lr][kg8], a2[n], 0, 0, 0);
            a2[n] = __builtin_amdgcn_mfma_f32_16x16x32_bf16(
                aa[1], *(const bf16x8*)&vT[n * 16 + lr][32 + kg8], a2[n], 0, 0, 0);
        }
        __syncthreads();
        #pragma unroll
        for (int n = 0; n < 4; ++n) {
            const int d = n * 16 + lr;
            #pragma unroll
            for (int j = 0; j < 4; ++j) {
                const int t = r0 + G * 4 + j;
                At[t][d] = f2bf(a2[n][j]);
            }
        }
    }
    __syncthreads();
    {
        const int row = tid >> 2;
        const int c0  = (tid & 3) * 16;
        short* dst = ctxb + ((size_t)bh * T_ + t0 + row) * NFEAT;
        *(bf16x8*)&dst[c0]     = *(const bf16x8*)&At[row][c0];
        *(bf16x8*)&dst[c0 + 8] = *(const bf16x8*)&At[row][c0 + 8];
    }
    if (tid < 64) rs_g[(size_t)bh * T_ + t0 + tid] = rs_l[tid];
}

// ---------------------------------------------------------------------------
// Exclusive prefix over chunks, bf16 cKV (fp32 accumulators).
// ---------------------------------------------------------------------------
__global__ __launch_bounds__(256) void prefix_scan(
    short* __restrict__ cKVb, float* __restrict__ cK)
{
    const int bh  = blockIdx.x >> 2;
    const int sl  = blockIdx.x & 3;
    const int tid = threadIdx.x;
    short* base = cKVb + (size_t)bh * NC_ * (NFEAT * HD) + sl * 1024 + tid * 4;
    bf16x4 n0 = *(const bf16x4*)(base);
    bf16x4 n1 = *(const bf16x4*)(base + 4096);
    float pref[4] = {0.0f, 0.0f, 0.0f, 0.0f};
    for (int c = 0; c < NC_; ++c) {
        bf16x4 cur = n0;
        n0 = n1;
        if (c + 2 < NC_) n1 = *(const bf16x4*)(base + (size_t)(c + 2) * 4096);
        else { n1[0] = 0; n1[1] = 0; n1[2] = 0; n1[3] = 0; }
        bf16x4 o = { f2bf(pref[0]), f2bf(pref[1]), f2bf(pref[2]), f2bf(pref[3]) };
        *(bf16x4*)(base + (size_t)c * 4096) = o;
        pref[0] += bf2f(cur[0]); pref[1] += bf2f(cur[1]);
        pref[2] += bf2f(cur[2]); pref[3] += bf2f(cur[3]);
    }
    if (sl == 0 && tid < 64) {
        float* kb = cK + (size_t)bh * NC_ * NFEAT + tid;
        float m0 = kb[0];
        float m1 = kb[64];
        float p = 0.0f;
        for (int c = 0; c < NC_; ++c) {
            float cu = m0;
            m0 = m1;
            m1 = (c + 2 < NC_) ? kb[(size_t)(c + 2) * 64] : 0.0f;
            kb[(size_t)c * 64] = p;
            p += cu;
        }
    }
}

// ---------------------------------------------------------------------------
// Inter-chunk term + finalize; ctx staged in via LDS, output staged out via
// LDS (Q region reused) -> coalesced bf16x8 row stores.
// ---------------------------------------------------------------------------
__global__ __launch_bounds__(256) void inter_attn(
    const short* __restrict__ qf,
    const short* __restrict__ ctxb,
    const float* __restrict__ rs_g,
    const short* __restrict__ cKVp,
    const float* __restrict__ cKp_g,
    short* __restrict__ attnb)
{
    __shared__ short Q[64][72];
    __shared__ short Pp[64][72];
    __shared__ short Ct[64][72];
    __shared__ float cKp[64], rs[64], qkp_l[64];

    const int tid = threadIdx.x;
    const int chunk = blockIdx.x;
    const int bh = chunk >> 6, c = chunk & 63;
    const int b = bh >> 4, h = bh & 15;
    const int t0 = c * 64;

    {
        const int row = tid >> 2;
        const int c0  = (tid & 3) * 16;
        const short* qrow = qf   + ((size_t)bh * T_ + t0 + row) * NFEAT;
        const short* crow = ctxb + ((size_t)bh * T_ + t0 + row) * NFEAT;
        const short* prow = cKVp + (size_t)chunk * (NFEAT * HD) + row * NFEAT;
        *(bf16x8*)&Q[row][c0]      = *(const bf16x8*)&qrow[c0];
        *(bf16x8*)&Q[row][c0 + 8]  = *(const bf16x8*)&qrow[c0 + 8];
        *(bf16x8*)&Ct[row][c0]     = *(const bf16x8*)&crow[c0];
        *(bf16x8*)&Ct[row][c0 + 8] = *(const bf16x8*)&crow[c0 + 8];
        *(bf16x8*)&Pp[row][c0]     = *(const bf16x8*)&prow[c0];
        *(bf16x8*)&Pp[row][c0 + 8] = *(const bf16x8*)&prow[c0 + 8];
        if (tid < 64) {
            cKp[tid] = cKp_g[(size_t)chunk * NFEAT + tid];
            rs[tid]  = rs_g[(size_t)bh * T_ + t0 + tid];
        }
    }
    __syncthreads();

    {
        const int t  = tid >> 2;
        const int fq = (tid & 3) * 16;
        float s = 0.0f;
        #pragma unroll
        for (int j = 0; j < 16; ++j) s += bf2f(Q[t][fq + j]) * cKp[fq + j];
        s += __shfl_xor(s, 1, 64);
        s += __shfl_xor(s, 2, 64);
        if ((tid & 3) == 0) qkp_l[t] = s;
    }

    const int wave = tid >> 6;
    const int lane = tid & 63;
    const int lr = lane & 15;
    const int G  = lane >> 4;
    const int kg = G * 8;
    const int r0 = wave * 16;

    bf16x8 aq[2];
    aq[0] = *(const bf16x8*)&Q[r0 + lr][kg];
    aq[1] = *(const bf16x8*)&Q[r0 + lr][32 + kg];
    f32x4 acc[4] = {};
    #pragma unroll
    for (int n = 0; n < 4; ++n) {
        acc[n] = __builtin_amdgcn_mfma_f32_16x16x32_bf16(
            aq[0], *(const bf16x8*)&Pp[n * 16 + lr][kg], acc[n], 0, 0, 0);
        acc[n] = __builtin_amdgcn_mfma_f32_16x16x32_bf16(
            aq[1], *(const bf16x8*)&Pp[n * 16 + lr][32 + kg], acc[n], 0, 0, 0);
    }
    __syncthreads();   // qkp_l visible; Q LDS reads complete -> reusable

    float inv[4];
    #pragma unroll
    for (int j = 0; j < 4; ++j) {
        const int t = r0 + G * 4 + j;
        inv[j] = 1.0f / fmaxf(rs[t] + qkp_l[t], 1e-6f);
    }
    // stage output tile into Q region [t][d], then coalesced row stores
    #pragma unroll
    for (int n = 0; n < 4; ++n) {
        const int d = n * 16 + lr;
        #pragma unroll
        for (int j = 0; j < 4; ++j) {
            const int t = r0 + G * 4 + j;
            Q[t][d] = f2bf((bf2f(Ct[t][d]) + acc[n][j]) * inv[j]);
        }
    }
    __syncthreads();
    {
        const int row = tid >> 2;
        const int c0  = (tid & 3) * 16;
        short* dst = attnb + ((size_t)(b * T_ + t0 + row)) * EMBED + h * HD;
        *(bf16x8*)&dst[c0]     = *(const bf16x8*)&Q[row][c0];
        *(bf16x8*)&dst[c0 + 8] = *(const bf16x8*)&Q[row][c0 + 8];
    }
}

// ---------------------------------------------------------------------------
extern "C" void kernel_launch(void* const* d_in, const int* in_sizes, int n_in,
                              void* d_out, int out_size, void* d_ws, size_t ws_size,
                              hipStream_t stream)
{
    const float* x     = (const float*)d_in[0];
    const float* w_qkv = (const float*)d_in[1];
    const float* b_qkv = (const float*)d_in[2];
    const float* w_out = (const float*)d_in[3];
    const float* b_out = (const float*)d_in[4];
    const float* omega = (const float*)d_in[5];
    const float* qn    = (const float*)d_in[6];
    const float* qw    = (const float*)d_in[7];
    float* out = (float*)d_out;

    short* xb    = (short*)d_ws;               //  8,388,608
    short* wqb   = xb    + 8388608;            //  3,145,728
    short* wob   = wqb   + 3145728;            //  1,048,576
    short* qkvb  = wob   + 1048576;            // 25,165,824
    short* attnb = qkvb  + 25165824;           //  8,388,608
    short* omgH  = attnb + 8388608;            //     65,536
    short* omgL  = omgH  + 65536;              //     65,536
    short* qfb   = omgL  + 65536;              //  8,388,608
    short* ctxb  = qfb   + 8388608;            //  8,388,608
    short* cKVb  = ctxb  + 8388608;            //  8,388,608
    float* cK    = (float*)(cKVb + 8388608);   //    131,072 floats
    float* rs_g  = cK + 131072;                //    131,072 floats

    const int M = B_ * T_;   // 8192

    prep_kernel<<<dim3((NV_ALL + 65536) / 256), 256, 0, stream>>>(
        x, w_qkv, w_out, omega, xb, wqb, wob, omgH, omgL);

    gemm_bf16<1><<<dim3((M / 128) * (THREEC / 128)), 256, 0, stream>>>(
        xb, wqb, b_qkv, nullptr, qkvb, M, THREEC, EMBED);
    feat_fused<<<dim3(BH_ * NC_), 256, 0, stream>>>(
        qkvb, omgH, omgL, qn, qw, qfb, ctxb, rs_g, cKVb, cK);
    prefix_scan<<<dim3(BH_ * 4), 256, 0, stream>>>(cKVb, cK);
    inter_attn<<<dim3(BH_ * NC_), 256, 0, stream>>>(
        qfb, ctxb, rs_g, cKVb, cK, attnb);
    gemm_bf16<0><<<dim3((EMBED / 128) * (M / 128)), 256, 0, stream>>>(
        attnb, wob, b_out, out, nullptr, M, EMBED, EMBED);
}

// Round 13
// 168.206 us; speedup vs baseline: 1.0076x; 1.0049x over previous
//
#include <hip/hip_runtime.h>
#include <math.h>

#define EMBED   1024
#define THREEC  3072
#define NH      16
#define HD      64
#define NFEAT   64      // R * M = 2 * 32
#define RN      2
#define MM_     32
#define B_      2
#define T_      4096
#define L_      64      // chunk length
#define NC_     64      // T_ / L_
#define BH_     32      // B_ * NH

typedef __attribute__((ext_vector_type(8))) short bf16x8;
typedef __attribute__((ext_vector_type(4))) short bf16x4;
typedef __attribute__((ext_vector_type(4))) float f32x4;

__device__ __forceinline__ float bf2f(short s) {
    unsigned u = ((unsigned)(unsigned short)s) << 16;
    return __builtin_bit_cast(float, u);
}
__device__ __forceinline__ short f2bf(float f) {
    unsigned u = __builtin_bit_cast(unsigned, f);
    u += 0x7fff + ((u >> 16) & 1);
    return (short)(u >> 16);
}
__device__ __forceinline__ void gload16(const short* g, short* l) {
    __builtin_amdgcn_global_load_lds(
        (const __attribute__((address_space(1))) void*)g,
        (__attribute__((address_space(3))) void*)l, 16, 0, 0);
}

// ---------------------------------------------------------------------------
// Fused prep: f32->bf16 casts for x, w_qkv, w_out + omega hi/lo transpose.
// ---------------------------------------------------------------------------
#define NV_X   1048576            // 8388608 / 8
#define NV_WQ  393216             // 3145728 / 8
#define NV_WO  131072             // 1048576 / 8
#define NV_ALL (NV_X + NV_WQ + NV_WO)
__global__ __launch_bounds__(256) void prep_kernel(
    const float* __restrict__ x, const float* __restrict__ wq,
    const float* __restrict__ wo, const float* __restrict__ omega,
    short* __restrict__ xb, short* __restrict__ wqb, short* __restrict__ wob,
    short* __restrict__ omgH, short* __restrict__ omgL)
{
    int i = blockIdx.x * 256 + threadIdx.x;
    if (i < NV_ALL) {
        const float* src; short* dst; int k;
        if (i < NV_X)            { src = x;  dst = xb;  k = i; }
        else if (i < NV_X+NV_WQ) { src = wq; dst = wqb; k = i - NV_X; }
        else                     { src = wo; dst = wob; k = i - NV_X - NV_WQ; }
        const float4* p = (const float4*)src + (size_t)k * 2;
        float4 a = p[0], b = p[1];
        bf16x8 o = { f2bf(a.x), f2bf(a.y), f2bf(a.z), f2bf(a.w),
                     f2bf(b.x), f2bf(b.y), f2bf(b.z), f2bf(b.w) };
        *((bf16x8*)dst + k) = o;
    } else {
        int j = i - NV_ALL;               // 0..65535 over H*F*D
        if (j < NH * NFEAT * HD) {
            int d = j & 63;
            int f = (j >> 6) & 63;
            int h = j >> 12;
            int r = f >> 5, m = f & 31;
            float w = omega[(((size_t)(r * NH + h) * HD + d) * MM_) + m];
            short a = f2bf(w);
            omgH[j] = a;
            omgL[j] = f2bf(w - bf2f(a));
        }
    }
}

// ---------------------------------------------------------------------------
// bf16 MFMA GEMM (m97 structure), 1D grid + XCD-aware M-stripe swizzle.
// LDS granule swizzle (slot = G ^ ((row>>1)&3)) applied on BOTH the
// global_load_lds source granule and the ds_read slot: rows 0-7 of each
// granule-group cover all 32 banks -> 2-way (free) instead of 8-way.
// ---------------------------------------------------------------------------
template<int OUTBF>
__global__ __launch_bounds__(256) void gemm_bf16(
    const short* __restrict__ A,      // [M][K] bf16
    const short* __restrict__ W,      // [N][K] bf16
    const float* __restrict__ bias,   // [N]
    float* __restrict__ Cf, short* __restrict__ Cb,
    int M, int N, int K)
{
    __shared__ short lA[2][128 * 32];
    __shared__ short lB[2][128 * 32];
    const int tid  = threadIdx.x;
    const int nbn  = N >> 7;
    const int cpx  = gridDim.x >> 3;
    const int swz  = (blockIdx.x & 7) * cpx + (blockIdx.x >> 3);
    const int bm   = (swz / nbn) << 7;
    const int bn   = (swz % nbn) << 7;
    const int lane = tid & 63;
    const int wave = tid >> 6;
    const int row0 = (wave >> 1) * 64;
    const int col0 = (wave & 1) * 64;
    const int lr   = lane & 15;
    const int G    = lane >> 4;

    f32x4 acc[4][4] = {};

#define STAGE(buf, k0)                                                        \
    {                                                                         \
        _Pragma("unroll")                                                     \
        for (int i = 0; i < 2; ++i) {                                         \
            int idx = i * 256 + tid;                                          \
            int row = idx >> 2;                                               \
            int gq  = (idx & 3) ^ ((row >> 1) & 3);                           \
            gload16(&A[(size_t)(bm + row) * K + (k0) + gq * 8], &lA[buf][idx * 8]); \
            gload16(&W[(size_t)(bn + row) * K + (k0) + gq * 8], &lB[buf][idx * 8]); \
        }                                                                     \
    }

    const int KT = K >> 5;
    STAGE(0, 0);
    __syncthreads();
    int cur = 0;
    for (int kt = 0; kt < KT; ++kt) {
        if (kt + 1 < KT) STAGE(cur ^ 1, (kt + 1) * 32);
        const short* As = lA[cur];
        const short* Bs = lB[cur];
        bf16x8 af[4], bfr[4];
        #pragma unroll
        for (int m = 0; m < 4; ++m) {
            const int ra = row0 + m * 16 + lr;
            af[m] = *(const bf16x8*)&As[ra * 32 + ((G ^ ((ra >> 1) & 3)) << 3)];
        }
        #pragma unroll
        for (int n = 0; n < 4; ++n) {
            const int rb = col0 + n * 16 + lr;
            bfr[n] = *(const bf16x8*)&Bs[rb * 32 + ((G ^ ((rb >> 1) & 3)) << 3)];
        }
        #pragma unroll
        for (int m = 0; m < 4; ++m)
            #pragma unroll
            for (int n = 0; n < 4; ++n)
                acc[m][n] = __builtin_amdgcn_mfma_f32_16x16x32_bf16(
                    af[m], bfr[n], acc[m][n], 0, 0, 0);
        __syncthreads();
        cur ^= 1;
    }
#undef STAGE

    #pragma unroll
    for (int n = 0; n < 4; ++n) {
        const int col = bn + col0 + n * 16 + (lane & 15);
        const float bvv = bias[col];
        #pragma unroll
        for (int m = 0; m < 4; ++m) {
            const int rbase = bm + row0 + m * 16 + (lane >> 4) * 4;
            #pragma unroll
            for (int j = 0; j < 4; ++j) {
                const float v = acc[m][n][j] + bvv;
                if (OUTBF) Cb[(size_t)(rbase + j) * N + col] = f2bf(v);
                else       Cf[(size_t)(rbase + j) * N + col] = v;
            }
        }
    }
}

// ---------------------------------------------------------------------------
// Fused: feature map + per-chunk KV sums + INTRA-chunk attention local part.
// LDS reuse: zq->kfT, zk->vT, omh->Qrm, oml->Krm->At->ctx-rows.
// ---------------------------------------------------------------------------
__global__ __launch_bounds__(256) void feat_fused(
    const short* __restrict__ qkvb,
    const short* __restrict__ omgH,
    const short* __restrict__ omgL,
    const float* __restrict__ qn,
    const float* __restrict__ qw,
    short* __restrict__ qf,
    short* __restrict__ ctxb,
    float* __restrict__ rs_g,
    short* __restrict__ cKVb,
    float* __restrict__ cK)
{
    __shared__ short zq[64][72];
    __shared__ short zk[64][72];
    __shared__ short omh[64][72];
    __shared__ short oml[64][72];
    __shared__ float invn[2][64];
    __shared__ float rs_l[64];

    const int tid   = threadIdx.x;
    const int chunk = blockIdx.x;
    const int bh    = chunk >> 6;
    const int c     = chunk & 63;
    const int b     = bh >> 4, h = bh & 15;
    const int t0    = c * 64;

    {
        const int row = tid >> 2;
        const int c0  = (tid & 3) * 16;
        const size_t zbase = ((size_t)(b * T_ + t0 + row)) * THREEC + h * HD + c0;
        const size_t obase = ((size_t)h * NFEAT + row) * HD + c0;
        *(bf16x8*)&zq[row][c0]      = *(const bf16x8*)&qkvb[zbase];
        *(bf16x8*)&zq[row][c0 + 8]  = *(const bf16x8*)&qkvb[zbase + 8];
        *(bf16x8*)&zk[row][c0]      = *(const bf16x8*)&qkvb[zbase + EMBED];
        *(bf16x8*)&zk[row][c0 + 8]  = *(const bf16x8*)&qkvb[zbase + EMBED + 8];
        *(bf16x8*)&omh[row][c0]     = *(const bf16x8*)&omgH[obase];
        *(bf16x8*)&omh[row][c0 + 8] = *(const bf16x8*)&omgH[obase + 8];
        *(bf16x8*)&oml[row][c0]     = *(const bf16x8*)&omgL[obase];
        *(bf16x8*)&oml[row][c0 + 8] = *(const bf16x8*)&omgL[obase + 8];
    }
    __syncthreads();

    {
        const int t = tid >> 2;
        const int q = tid & 3;
        #pragma unroll
        for (int p = 0; p < 2; ++p) {
            const short* Z = p ? &zk[t][q * 16] : &zq[t][q * 16];
            float ss = 0.0f;
            #pragma unroll
            for (int j = 0; j < 16; ++j) { float v = bf2f(Z[j]); ss += v * v; }
            ss += __shfl_xor(ss, 1, 64);
            ss += __shfl_xor(ss, 2, 64);
            if (q == 0) invn[p][t] = 1.0f / fmaxf(sqrtf(ss), 1e-12f);
        }
    }
    __syncthreads();

    const int wave = tid >> 6;
    const int lane = tid & 63;
    const int p    = wave >> 1;
    const int half = wave & 1;
    const short (*Z)[72] = p ? zk : zq;

    const float s0 = qn[0], s1 = qn[1];
    const float sq2s0 = sqrtf(2.0f * fmaxf(s0, 0.0f));
    const float sq2s1 = sqrtf(2.0f * fmaxf(s1, 0.0f));
    const float sc0 = sqrtf(fmaxf(qw[0], 0.0f)) * (1.0f / 32.0f);
    const float sc1 = sqrtf(fmaxf(qw[1], 0.0f)) * (1.0f / 32.0f);

    const int lr  = lane & 15;
    const int G   = lane >> 4;
    const int kg8 = G * 8;

    f32x4 acc[2][4] = {};
    #pragma unroll
    for (int kk = 0; kk < 2; ++kk) {
        bf16x8 a[2], bh8[4], bl8[4];
        #pragma unroll
        for (int m = 0; m < 2; ++m)
            a[m] = *(const bf16x8*)&Z[half * 32 + m * 16 + lr][kk * 32 + kg8];
        #pragma unroll
        for (int n = 0; n < 4; ++n) {
            bh8[n] = *(const bf16x8*)&omh[n * 16 + lr][kk * 32 + kg8];
            bl8[n] = *(const bf16x8*)&oml[n * 16 + lr][kk * 32 + kg8];
        }
        #pragma unroll
        for (int m = 0; m < 2; ++m)
            #pragma unroll
            for (int n = 0; n < 4; ++n) {
                acc[m][n] = __builtin_amdgcn_mfma_f32_16x16x32_bf16(
                    a[m], bh8[n], acc[m][n], 0, 0, 0);
                acc[m][n] = __builtin_amdgcn_mfma_f32_16x16x32_bf16(
                    a[m], bl8[n], acc[m][n], 0, 0, 0);
            }
    }
    __syncthreads();

    short (*kfT)[72] = zq;
    short (*vT)[72]  = zk;
    short (*Qrm)[72] = omh;
    short (*Krm)[72] = oml;
    {
        #pragma unroll
        for (int n = 0; n < 4; ++n) {
            const int f = n * 16 + lr;
            const float s_r   = (n < 2) ? s0 : s1;
            const float sq2s  = (n < 2) ? sq2s0 : sq2s1;
            const float scale = (n < 2) ? sc0 : sc1;
            #pragma unroll
            for (int m = 0; m < 2; ++m) {
                const int tb4 = half * 32 + m * 16 + G * 4;
                #pragma unroll
                for (int j = 0; j < 4; ++j) {
                    const int t = tb4 + j;
                    const float proj = acc[m][n][j] * invn[p][t];
                    const float arg = fminf(fmaxf(proj * sq2s - s_r, -20.0f), 20.0f);
                    const float val = proj * proj * __expf(arg) * scale;
                    const short vb  = f2bf(val);
                    if (p == 0) { Qrm[t][f] = vb; }
                    else        { kfT[f][t] = vb; Krm[t][f] = vb; }
                }
            }
        }
    }
    {
        const int row = tid >> 2;
        const int c0  = (tid & 3) * 16;
        const short* vrow = qkvb + ((size_t)(b * T_ + t0 + row)) * THREEC
                          + 2 * EMBED + h * HD;
        bf16x8 v0 = *(const bf16x8*)&vrow[c0], v1 = *(const bf16x8*)&vrow[c0 + 8];
        #pragma unroll
        for (int j = 0; j < 8; ++j) {
            vT[c0 + j][row]     = v0[j];
            vT[c0 + 8 + j][row] = v1[j];
        }
    }
    __syncthreads();

    const int r0 = wave * 16;

    {
        const int row = tid >> 2;
        const int c0  = (tid & 3) * 16;
        short* dst = qf + ((size_t)bh * T_ + t0 + row) * NFEAT;
        *(bf16x8*)&dst[c0]     = *(const bf16x8*)&Qrm[row][c0];
        *(bf16x8*)&dst[c0 + 8] = *(const bf16x8*)&Qrm[row][c0 + 8];
    }
    bf16x8 aqq[2];
    aqq[0] = *(const bf16x8*)&Qrm[r0 + lr][kg8];
    aqq[1] = *(const bf16x8*)&Qrm[r0 + lr][32 + kg8];
    f32x4 accA[4] = {};
    #pragma unroll
    for (int n = 0; n < 4; ++n) {
        accA[n] = __builtin_amdgcn_mfma_f32_16x16x32_bf16(
            aqq[0], *(const bf16x8*)&Krm[n * 16 + lr][kg8], accA[n], 0, 0, 0);
        accA[n] = __builtin_amdgcn_mfma_f32_16x16x32_bf16(
            aqq[1], *(const bf16x8*)&Krm[n * 16 + lr][32 + kg8], accA[n], 0, 0, 0);
    }
    {
        float rsum[4] = {0.0f, 0.0f, 0.0f, 0.0f};
        #pragma unroll
        for (int n = 0; n < 4; ++n) {
            const int s = n * 16 + lr;
            #pragma unroll
            for (int j = 0; j < 4; ++j) {
                const int t = r0 + G * 4 + j;
                if (s <= t) rsum[j] += accA[n][j];
            }
        }
        #pragma unroll
        for (int j = 0; j < 4; ++j) {
            rsum[j] += __shfl_xor(rsum[j], 1, 64);
            rsum[j] += __shfl_xor(rsum[j], 2, 64);
            rsum[j] += __shfl_xor(rsum[j], 4, 64);
            rsum[j] += __shfl_xor(rsum[j], 8, 64);
        }
        if (lr == 0) {
            #pragma unroll
            for (int j = 0; j < 4; ++j) rs_l[r0 + G * 4 + j] = rsum[j];
        }
    }
    {
        bf16x8 a2[2];
        a2[0] = *(const bf16x8*)&kfT[wave * 16 + lr][kg8];
        a2[1] = *(const bf16x8*)&kfT[wave * 16 + lr][32 + kg8];
        f32x4 sa[4] = {};
        #pragma unroll
        for (int n = 0; n < 4; ++n) {
            sa[n] = __builtin_amdgcn_mfma_f32_16x16x32_bf16(
                a2[0], *(const bf16x8*)&vT[n * 16 + lr][kg8], sa[n], 0, 0, 0);
            sa[n] = __builtin_amdgcn_mfma_f32_16x16x32_bf16(
                a2[1], *(const bf16x8*)&vT[n * 16 + lr][32 + kg8], sa[n], 0, 0, 0);
        }
        short* basep = cKVb + (size_t)chunk * (NFEAT * HD);
        #pragma unroll
        for (int n = 0; n < 4; ++n) {
            bf16x4 o = { f2bf(sa[n][0]), f2bf(sa[n][1]),
                         f2bf(sa[n][2]), f2bf(sa[n][3]) };
            *(bf16x4*)&basep[(n * 16 + lr) * NFEAT + wave * 16 + G * 4] = o;
        }
    }
    {
        const int f  = tid >> 2;
        const int tq = tid & 3;
        float s = 0.0f;
        #pragma unroll
        for (int j = 0; j < 16; ++j) s += bf2f(kfT[f][tq * 16 + j]);
        s += __shfl_xor(s, 1, 64);
        s += __shfl_xor(s, 2, 64);
        if (tq == 0) cK[(size_t)chunk * NFEAT + f] = s;
    }
    __syncthreads();

    short (*At)[72] = oml;
    #pragma unroll
    for (int n = 0; n < 4; ++n) {
        const int s = n * 16 + lr;
        #pragma unroll
        for (int j = 0; j < 4; ++j) {
            const int t = r0 + G * 4 + j;
            At[t][s] = f2bf((s <= t) ? accA[n][j] : 0.0f);
        }
    }
    __syncthreads();

    {
        bf16x8 aa[2];
        aa[0] = *(const bf16x8*)&At[r0 + lr][kg8];
        aa[1] = *(const bf16x8*)&At[r0 + lr][32 + kg8];
        f32x4 a2[4] = {};
        #pragma unroll
        for (int n = 0; n < 4; ++n) {
            a2[n] = __builtin_amdgcn_mfma_f32_16x16x32_bf16(
                aa[0], *(const bf16x8*)&vT[n * 16 + lr][kg8], a2[n], 0, 0, 0);
            a2[n] = __builtin_amdgcn_mfma_f32_16x16x32_bf16(
                aa[1], *(const bf16x8*)&vT[n * 16 + lr][32 + kg8], a2[n], 0, 0, 0);
        }
        __syncthreads();
        #pragma unroll
        for (int n = 0; n < 4; ++n) {
            const int d = n * 16 + lr;
            #pragma unroll
            for (int j = 0; j < 4; ++j) {
                const int t = r0 + G * 4 + j;
                At[t][d] = f2bf(a2[n][j]);
            }
        }
    }
    __syncthreads();
    {
        const int row = tid >> 2;
        const int c0  = (tid & 3) * 16;
        short* dst = ctxb + ((size_t)bh * T_ + t0 + row) * NFEAT;
        *(bf16x8*)&dst[c0]     = *(const bf16x8*)&At[row][c0];
        *(bf16x8*)&dst[c0 + 8] = *(const bf16x8*)&At[row][c0 + 8];
    }
    if (tid < 64) rs_g[(size_t)bh * T_ + t0 + tid] = rs_l[tid];
}

// ---------------------------------------------------------------------------
// Exclusive prefix over chunks, bf16 cKV (fp32 accumulators).
// ---------------------------------------------------------------------------
__global__ __launch_bounds__(256) void prefix_scan(
    short* __restrict__ cKVb, float* __restrict__ cK)
{
    const int bh  = blockIdx.x >> 2;
    const int sl  = blockIdx.x & 3;
    const int tid = threadIdx.x;
    short* base = cKVb + (size_t)bh * NC_ * (NFEAT * HD) + sl * 1024 + tid * 4;
    bf16x4 n0 = *(const bf16x4*)(base);
    bf16x4 n1 = *(const bf16x4*)(base + 4096);
    float pref[4] = {0.0f, 0.0f, 0.0f, 0.0f};
    for (int c = 0; c < NC_; ++c) {
        bf16x4 cur = n0;
        n0 = n1;
        if (c + 2 < NC_) n1 = *(const bf16x4*)(base + (size_t)(c + 2) * 4096);
        else { n1[0] = 0; n1[1] = 0; n1[2] = 0; n1[3] = 0; }
        bf16x4 o = { f2bf(pref[0]), f2bf(pref[1]), f2bf(pref[2]), f2bf(pref[3]) };
        *(bf16x4*)(base + (size_t)c * 4096) = o;
        pref[0] += bf2f(cur[0]); pref[1] += bf2f(cur[1]);
        pref[2] += bf2f(cur[2]); pref[3] += bf2f(cur[3]);
    }
    if (sl == 0 && tid < 64) {
        float* kb = cK + (size_t)bh * NC_ * NFEAT + tid;
        float m0 = kb[0];
        float m1 = kb[64];
        float p = 0.0f;
        for (int c = 0; c < NC_; ++c) {
            float cu = m0;
            m0 = m1;
            m1 = (c + 2 < NC_) ? kb[(size_t)(c + 2) * 64] : 0.0f;
            kb[(size_t)c * 64] = p;
            p += cu;
        }
    }
}

// ---------------------------------------------------------------------------
// Inter-chunk term + finalize; ctx staged in via LDS, output staged out via
// LDS (Q region reused) -> coalesced bf16x8 row stores.
// ---------------------------------------------------------------------------
__global__ __launch_bounds__(256) void inter_attn(
    const short* __restrict__ qf,
    const short* __restrict__ ctxb,
    const float* __restrict__ rs_g,
    const short* __restrict__ cKVp,
    const float* __restrict__ cKp_g,
    short* __restrict__ attnb)
{
    __shared__ short Q[64][72];
    __shared__ short Pp[64][72];
    __shared__ short Ct[64][72];
    __shared__ float cKp[64], rs[64], qkp_l[64];

    const int tid = threadIdx.x;
    const int chunk = blockIdx.x;
    const int bh = chunk >> 6, c = chunk & 63;
    const int b = bh >> 4, h = bh & 15;
    const int t0 = c * 64;

    {
        const int row = tid >> 2;
        const int c0  = (tid & 3) * 16;
        const short* qrow = qf   + ((size_t)bh * T_ + t0 + row) * NFEAT;
        const short* crow = ctxb + ((size_t)bh * T_ + t0 + row) * NFEAT;
        const short* prow = cKVp + (size_t)chunk * (NFEAT * HD) + row * NFEAT;
        *(bf16x8*)&Q[row][c0]      = *(const bf16x8*)&qrow[c0];
        *(bf16x8*)&Q[row][c0 + 8]  = *(const bf16x8*)&qrow[c0 + 8];
        *(bf16x8*)&Ct[row][c0]     = *(const bf16x8*)&crow[c0];
        *(bf16x8*)&Ct[row][c0 + 8] = *(const bf16x8*)&crow[c0 + 8];
        *(bf16x8*)&Pp[row][c0]     = *(const bf16x8*)&prow[c0];
        *(bf16x8*)&Pp[row][c0 + 8] = *(const bf16x8*)&prow[c0 + 8];
        if (tid < 64) {
            cKp[tid] = cKp_g[(size_t)chunk * NFEAT + tid];
            rs[tid]  = rs_g[(size_t)bh * T_ + t0 + tid];
        }
    }
    __syncthreads();

    {
        const int t  = tid >> 2;
        const int fq = (tid & 3) * 16;
        float s = 0.0f;
        #pragma unroll
        for (int j = 0; j < 16; ++j) s += bf2f(Q[t][fq + j]) * cKp[fq + j];
        s += __shfl_xor(s, 1, 64);
        s += __shfl_xor(s, 2, 64);
        if ((tid & 3) == 0) qkp_l[t] = s;
    }

    const int wave = tid >> 6;
    const int lane = tid & 63;
    const int lr = lane & 15;
    const int G  = lane >> 4;
    const int kg = G * 8;
    const int r0 = wave * 16;

    bf16x8 aq[2];
    aq[0] = *(const bf16x8*)&Q[r0 + lr][kg];
    aq[1] = *(const bf16x8*)&Q[r0 + lr][32 + kg];
    f32x4 acc[4] = {};
    #pragma unroll
    for (int n = 0; n < 4; ++n) {
        acc[n] = __builtin_amdgcn_mfma_f32_16x16x32_bf16(
            aq[0], *(const bf16x8*)&Pp[n * 16 + lr][kg], acc[n], 0, 0, 0);
        acc[n] = __builtin_amdgcn_mfma_f32_16x16x32_bf16(
            aq[1], *(const bf16x8*)&Pp[n * 16 + lr][32 + kg], acc[n], 0, 0, 0);
    }
    __syncthreads();   // qkp_l visible; Q LDS reads complete -> reusable

    float inv[4];
    #pragma unroll
    for (int j = 0; j < 4; ++j) {
        const int t = r0 + G * 4 + j;
        inv[j] = 1.0f / fmaxf(rs[t] + qkp_l[t], 1e-6f);
    }
    // stage output tile into Q region [t][d], then coalesced row stores
    #pragma unroll
    for (int n = 0; n < 4; ++n) {
        const int d = n * 16 + lr;
        #pragma unroll
        for (int j = 0; j < 4; ++j) {
            const int t = r0 + G * 4 + j;
            Q[t][d] = f2bf((bf2f(Ct[t][d]) + acc[n][j]) * inv[j]);
        }
    }
    __syncthreads();
    {
        const int row = tid >> 2;
        const int c0  = (tid & 3) * 16;
        short* dst = attnb + ((size_t)(b * T_ + t0 + row)) * EMBED + h * HD;
        *(bf16x8*)&dst[c0]     = *(const bf16x8*)&Q[row][c0];
        *(bf16x8*)&dst[c0 + 8] = *(const bf16x8*)&Q[row][c0 + 8];
    }
}

// ---------------------------------------------------------------------------
extern "C" void kernel_launch(void* const* d_in, const int* in_sizes, int n_in,
                              void* d_out, int out_size, void* d_ws, size_t ws_size,
                              hipStream_t stream)
{
    const float* x     = (const float*)d_in[0];
    const float* w_qkv = (const float*)d_in[1];
    const float* b_qkv = (const float*)d_in[2];
    const float* w_out = (const float*)d_in[3];
    const float* b_out = (const float*)d_in[4];
    const float* omega = (const float*)d_in[5];
    const float* qn    = (const float*)d_in[6];
    const float* qw    = (const float*)d_in[7];
    float* out = (float*)d_out;

    short* xb    = (short*)d_ws;               //  8,388,608
    short* wqb   = xb    + 8388608;            //  3,145,728
    short* wob   = wqb   + 3145728;            //  1,048,576
    short* qkvb  = wob   + 1048576;            // 25,165,824
    short* attnb = qkvb  + 25165824;           //  8,388,608
    short* omgH  = attnb + 8388608;            //     65,536
    short* omgL  = omgH  + 65536;              //     65,536
    short* qfb   = omgL  + 65536;              //  8,388,608
    short* ctxb  = qfb   + 8388608;            //  8,388,608
    short* cKVb  = ctxb  + 8388608;            //  8,388,608
    float* cK    = (float*)(cKVb + 8388608);   //    131,072 floats
    float* rs_g  = cK + 131072;                //    131,072 floats

    const int M = B_ * T_;   // 8192

    prep_kernel<<<dim3((NV_ALL + 65536) / 256), 256, 0, stream>>>(
        x, w_qkv, w_out, omega, xb, wqb, wob, omgH, omgL);

    gemm_bf16<1><<<dim3((M / 128) * (THREEC / 128)), 256, 0, stream>>>(
        xb, wqb, b_qkv, nullptr, qkvb, M, THREEC, EMBED);
    feat_fused<<<dim3(BH_ * NC_), 256, 0, stream>>>(
        qkvb, omgH, omgL, qn, qw, qfb, ctxb, rs_g, cKVb, cK);
    prefix_scan<<<dim3(BH_ * 4), 256, 0, stream>>>(cKVb, cK);
    inter_attn<<<dim3(BH_ * NC_), 256, 0, stream>>>(
        qfb, ctxb, rs_g, cKVb, cK, attnb);
    gemm_bf16<0><<<dim3((EMBED / 128) * (M / 128)), 256, 0, stream>>>(
        attnb, wob, b_out, out, nullptr, M, EMBED, EMBED);
}